// Round 16
// baseline (1458.967 us; speedup 1.0000x reference)
//
#include <hip/hip_runtime.h>
#include <math.h>

#define N_NODES 30000
#define N_EDGES 480000
#define DEGN 0.25f   // 1/sqrt(16)
#define NBLK 1875    // N_EDGES/256
#define TPITCH 52    // odd dword stride -> conflict-free (verified: 1.32M -> 0)

// Phase fence: stops IR motion + backend scheduling across phase boundaries
// (round-9 lesson: unrestricted motion -> live-range blowup -> 2 GB spill).
#define FENCE() do { asm volatile("" ::: "memory"); __builtin_amdgcn_sched_barrier(0); } while(0)

typedef __attribute__((ext_vector_type(8))) short short8;
typedef __attribute__((ext_vector_type(4))) float f32x4;

__device__ __forceinline__ float fsilu(float x){ return x / (1.f + __expf(-x)); }
__device__ __forceinline__ float fsig (float x){ return 1.f / (1.f + __expf(-x)); }

__device__ __forceinline__ unsigned bf16rn(float x){
  unsigned u = __float_as_uint(x);
  return (u + 0x7fffu + ((u>>16)&1u)) >> 16;
}
__device__ __forceinline__ unsigned pack2(float a, float b){
  return bf16rn(a) | (bf16rn(b)<<16);
}
__device__ __forceinline__ float bflo(unsigned u){ return __uint_as_float(u<<16); }
__device__ __forceinline__ float bfhi(unsigned u){ return __uint_as_float(u & 0xffff0000u); }

// ==================== degree counts (src and dst) ====================
__global__ __launch_bounds__(256) void count2(const int* __restrict__ ei,
                                              int* __restrict__ deg_src,
                                              int* __restrict__ deg_dst)
{
  int e = blockIdx.x*256 + threadIdx.x;
  if (e >= N_EDGES) return;
  atomicAdd(deg_src + ei[e], 1);
  atomicAdd(deg_dst + ei[N_EDGES + e], 1);
}

// 2 blocks: block 0 scans src arrays, block 1 scans dst arrays
__global__ __launch_bounds__(1024) void scan_deg2(
    const int* __restrict__ deg_src, int* __restrict__ off_src, int* __restrict__ cur_src,
    const int* __restrict__ deg_dst, int* __restrict__ off_dst, int* __restrict__ cur_dst)
{
  const int* deg = blockIdx.x ? deg_dst : deg_src;
  int* off = blockIdx.x ? off_dst : off_src;
  int* cur = blockIdx.x ? cur_dst : cur_src;
  __shared__ int part[1024];
  int t = threadIdx.x;
  int base = t*30;
  int local[30];
  int s = 0;
  #pragma unroll
  for (int i=0;i<30;i++){
    int idx = base + i;
    int d = (idx < N_NODES) ? deg[idx] : 0;
    local[i] = s; s += d;
  }
  part[t] = s; __syncthreads();
  for (int stp=1; stp<1024; stp<<=1){
    int v = (t >= stp) ? part[t-stp] : 0;
    __syncthreads();
    part[t] += v;
    __syncthreads();
  }
  int prefix = (t==0) ? 0 : part[t-1];
  #pragma unroll
  for (int i=0;i<30;i++){
    int idx = base + i;
    if (idx < N_NODES){ int o = prefix + local[i]; off[idx] = o; cur[idx] = o; }
  }
  if (t == 1023) off[N_NODES] = part[1023];
}

// src-order scatter: csr_src[m]=e, pos_src[e]=m
__global__ __launch_bounds__(256) void scatter_src(const int* __restrict__ ei,
                                                   int* __restrict__ cur,
                                                   int* __restrict__ csr_src,
                                                   int* __restrict__ pos_src)
{
  int e = blockIdx.x*256 + threadIdx.x;
  if (e >= N_EDGES) return;
  int p = atomicAdd(cur + ei[e], 1);
  csr_src[p] = e;
  pos_src[e] = p;
}

// dst-order scatter of src-positions: gidx[k] = pos_src[e]
__global__ __launch_bounds__(256) void scatter_dst(const int* __restrict__ ei,
                                                   const int* __restrict__ pos_src,
                                                   int* __restrict__ cur,
                                                   int* __restrict__ gidx)
{
  int e = blockIdx.x*256 + threadIdx.x;
  if (e >= N_EDGES) return;
  int p = atomicAdd(cur + ei[N_EDGES + e], 1);
  gidx[p] = pos_src[e];
}

// ==================== per-edge record in SRC order ====================
// rec[k] = 48 B: 8 u32 (16 bf16 ea) | y1x,y1y,y1z f32 | src int
__global__ __launch_bounds__(256) void prep_edges2(
    const float* __restrict__ pos, const int* __restrict__ ei,
    const int* __restrict__ bond_mask, const float* __restrict__ bond_emb,
    const int* __restrict__ csr_src, uint4* __restrict__ rec)
{
  int k = blockIdx.x*256 + threadIdx.x;
  if (k >= N_EDGES) return;
  int e = csr_src[k];
  int src = ei[e], dst = ei[N_EDGES + e];
  float ax = pos[src*3+0], ay = pos[src*3+1], az = pos[src*3+2];
  float bx = pos[dst*3+0], by = pos[dst*3+1], bz = pos[dst*3+2];
  float vx = ax-bx, vy = ay-by, vz = az-bz;
  float r = sqrtf(vx*vx + vy*vy + vz*vz);
  float inv = 1.f / fmaxf(r, 1e-9f);
  const float s3 = 1.7320508075688772f;
  float yx = s3*vx*inv, yy = s3*vy*inv, yz = s3*vz*inv;
  int bm = bond_mask[e];
  float eav[16];
  #pragma unroll
  for (int q=0;q<8;q++) eav[q] = bond_emb[bm*8+q];
  const float step = 5.0f/9.0f;
  #pragma unroll
  for (int j=0;j<8;j++){
    float vj = (float)(j+1)*step;
    float d = (r - vj)/step;
    eav[8+j] = __expf(-d*d) * (1.0f/1.12f);
  }
  uint4 r0, r1, r2;
  r0.x = pack2(eav[0],eav[1]);  r0.y = pack2(eav[2],eav[3]);
  r0.z = pack2(eav[4],eav[5]);  r0.w = pack2(eav[6],eav[7]);
  r1.x = pack2(eav[8],eav[9]);  r1.y = pack2(eav[10],eav[11]);
  r1.z = pack2(eav[12],eav[13]);r1.w = pack2(eav[14],eav[15]);
  r2.x = __float_as_uint(yx); r2.y = __float_as_uint(yy);
  r2.z = __float_as_uint(yz); r2.w = (unsigned)src;
  rec[(size_t)k*3+0] = r0;
  rec[(size_t)k*3+1] = r1;
  rec[(size_t)k*3+2] = r2;
}

// ==================== W2 -> bf16 hi/lo, [176][64] ====================
__global__ void prep_weights(const float* __restrict__ w2,
                             unsigned short* __restrict__ w2hi,
                             unsigned short* __restrict__ w2lo)
{
  int i = blockIdx.x*256 + threadIdx.x;
  if (i >= 3*176*64) return;
  int l = i / (176*64); int rem = i - l*(176*64);
  int n = rem / 64, k = rem - n*64;
  float w = w2[(size_t)l*64*176 + (size_t)k*176 + n];
  unsigned hi = bf16rn(w);
  float lo = w - __uint_as_float(hi<<16);
  w2hi[i] = (unsigned short)hi;
  w2lo[i] = (unsigned short)bf16rn(lo);
}

// ==================== init s ====================
__global__ __launch_bounds__(256) void init_nodes(
    const int* __restrict__ atom_type, const float* __restrict__ atom_emb,
    const float* __restrict__ w_init, float* __restrict__ s)
{
  int n = blockIdx.x*256 + threadIdx.x;
  if (n >= N_NODES) return;
  int t = atom_type[n];
  float acc[64];
  #pragma unroll
  for (int o=0;o<64;o++) acc[o]=0.f;
  for (int k=0;k<64;k++){
    float ek = atom_emb[t*64+k];
    #pragma unroll
    for (int o=0;o<64;o++) acc[o] = fmaf(ek, w_init[k*64+o], acc[o]);
  }
  float4* so = (float4*)(s + (size_t)n*64);
  #pragma unroll
  for (int q=0;q<16;q++) so[q] = make_float4(acc[4*q],acc[4*q+1],acc[4*q+2],acc[4*q+3]);
}

// ==================== fused edge kernel (round 16) ====================
// Round-15 structure with num_vgpr(168) EXACTLY (round 15's 170 request
// rounded up to 172 > 512/3 -> still 2 waves/SIMD). 3*168 = 504 <= 512
// -> 3 waves/SIMD; LDS 32 KB allows it. Both constraints now satisfied
// simultaneously for the first time.
__device__ __forceinline__ void mfma_tile(
    const unsigned short* __restrict__ W2hi, const unsigned short* __restrict__ W2lo,
    int colbase, const short8 (&bfr)[4][2], int wv, int l, unsigned char* tb)
{
  const unsigned short* ap = W2hi + (size_t)(colbase+(l&15))*64 + ((l>>4)*8);
  const unsigned short* aq = W2lo + (size_t)(colbase+(l&15))*64 + ((l>>4)*8);
  short8 ah0 = *(const short8*)ap;
  short8 ah1 = *(const short8*)(ap+32);
  short8 al0 = *(const short8*)aq;
  short8 al1 = *(const short8*)(aq+32);
  #pragma unroll
  for (int ntg=0;ntg<4;ntg++){
    f32x4 acc = {0.f,0.f,0.f,0.f};
    acc = __builtin_amdgcn_mfma_f32_16x16x32_bf16(ah0, bfr[ntg][0], acc, 0,0,0);
    acc = __builtin_amdgcn_mfma_f32_16x16x32_bf16(ah1, bfr[ntg][1], acc, 0,0,0);
    acc = __builtin_amdgcn_mfma_f32_16x16x32_bf16(al0, bfr[ntg][0], acc, 0,0,0);
    acc = __builtin_amdgcn_mfma_f32_16x16x32_bf16(al1, bfr[ntg][1], acc, 0,0,0);
    int e = wv*64 + ntg*16 + (l&15);
    uint2 pk; pk.x = pack2(acc[0],acc[1]); pk.y = pack2(acc[2],acc[3]);
    *(uint2*)(tb + (size_t)e*TPITCH + ((l>>4)*8)) = pk;
  }
}

__device__ __forceinline__ void decode_w(const unsigned char* tb, int t, float* w)
{
  const unsigned char* wr = tb + (size_t)t*TPITCH;
  uint4 c0 = *(const uint4*)wr;
  uint4 c1 = *(const uint4*)(wr+16);
  w[0]=bflo(c0.x); w[1]=bfhi(c0.x); w[2]=bflo(c0.y); w[3]=bfhi(c0.y);
  w[4]=bflo(c0.z); w[5]=bfhi(c0.z); w[6]=bflo(c0.w); w[7]=bfhi(c0.w);
  w[8]=bflo(c1.x); w[9]=bfhi(c1.x); w[10]=bflo(c1.y); w[11]=bfhi(c1.y);
  w[12]=bflo(c1.z); w[13]=bfhi(c1.z); w[14]=bflo(c1.w); w[15]=bfhi(c1.w);
}

__global__ __launch_bounds__(256) __attribute__((amdgpu_num_vgpr(168)))
void edge_fused2(
    const uint4* __restrict__ rec,
    const float* __restrict__ s, const float* __restrict__ v,
    const float* __restrict__ W1,      // [16][64] f32
    const float* __restrict__ b1,      // [64] f32
    const unsigned short* __restrict__ W2hi, // [176][64] bf16
    const unsigned short* __restrict__ W2lo, // [176][64] bf16
    const float* __restrict__ linv,    // [96][16] f32
    uint4* __restrict__ msg4)          // pair-interleaved, src-order index
{
  // H occupies [0,32768) during phase H / B-frag load; after the single
  // barrier, tiles overlay: tbA [0,13312), tbB [13312,26624).
  __shared__ __align__(16) unsigned char lds[32768];
  int t = threadIdx.x;
  int ke = blockIdx.x*256 + t;

  uint4 r0 = rec[(size_t)ke*3+0];
  uint4 r1 = rec[(size_t)ke*3+1];
  uint4 r2 = rec[(size_t)ke*3+2];
  float yx = __uint_as_float(r2.x), yy = __uint_as_float(r2.y), yz = __uint_as_float(r2.z);
  int src = (int)r2.w;

  // ---- phase H: h = silu(ea@W1+b1) -> LDS, in TWO 32-wide halves ----
  {
    float eav[16];
    eav[0]=bflo(r0.x); eav[1]=bfhi(r0.x); eav[2]=bflo(r0.y); eav[3]=bfhi(r0.y);
    eav[4]=bflo(r0.z); eav[5]=bfhi(r0.z); eav[6]=bflo(r0.w); eav[7]=bfhi(r0.w);
    eav[8]=bflo(r1.x); eav[9]=bfhi(r1.x); eav[10]=bflo(r1.y); eav[11]=bfhi(r1.y);
    eav[12]=bflo(r1.z); eav[13]=bfhi(r1.z); eav[14]=bflo(r1.w); eav[15]=bfhi(r1.w);
    #pragma unroll 1
    for (int hh=0; hh<2; ++hh){
      int kb = hh*32;
      float h[32];
      #pragma unroll
      for (int k=0;k<32;k++) h[k] = b1[kb+k];
      #pragma unroll
      for (int j=0;j<16;j++){
        float a = eav[j];
        #pragma unroll
        for (int k=0;k<32;k++) h[k] = fmaf(a, W1[j*64+kb+k], h[k]);
      }
      #pragma unroll
      for (int k=0;k<32;k++) h[k] = fsilu(h[k]);
      #pragma unroll
      for (int q=0;q<4;q++){
        uint4 hp;
        hp.x = pack2(h[8*q+0],h[8*q+1]); hp.y = pack2(h[8*q+2],h[8*q+3]);
        hp.z = pack2(h[8*q+4],h[8*q+5]); hp.w = pack2(h[8*q+6],h[8*q+7]);
        int byte = (t*128 + (hh*4+q)*16) ^ ((t&7)<<4);
        *(uint4*)(lds + byte) = hp;
      }
      FENCE();
    }
  }
  FENCE();

  // ---- B-fragments (H rows = this wave's own 64 edges) ----
  int wv = t>>6, l = t&63;
  short8 bfr[4][2];
  #pragma unroll
  for (int ntg=0;ntg<4;ntg++){
    int erow = wv*64 + ntg*16 + (l&15);
    #pragma unroll
    for (int kk=0;kk<2;kk++){
      int byte = (erow*128 + kk*64 + ((l>>4)*16)) ^ ((erow&7)<<4);
      bfr[ntg][kk] = *(const short8*)(lds + byte);
    }
  }
  __syncthreads();   // ALL waves done reading H before tiles overlay it

  unsigned char* tbA = lds;
  unsigned char* tbB = lds + 13312;
  const float* ssrc = s + (size_t)src*64;
  const float4* vsrc4 = (const float4*)(v + (size_t)src*48);
  uint4* mrow = msg4 + ((size_t)(ke>>1))*32 + (ke&1);

  // ---- sv tiles (cols 80..143): build a_o (needs per-edge transpose via LDS) ----
  float a_o[16];
  #pragma unroll
  for (int o=0;o<16;o++) a_o[o]=0.f;
  #pragma unroll 1
  for (int st=0; st<4; ++st){
    unsigned char* tb = (st&1) ? tbB : tbA;
    mfma_tile(W2hi, W2lo, 80+st*16, bfr, wv, l, tb);
    FENCE();
    float w[16]; decode_w(tb, t, w);
    int i0 = st*16;
    #pragma unroll
    for (int q4=0;q4<4;q4++){
      float4 s4 = *(const float4*)(ssrc + i0 + q4*4);
      float tq[4] = { w[q4*4+0]*s4.x, w[q4*4+1]*s4.y, w[q4*4+2]*s4.z, w[q4*4+3]*s4.w };
      #pragma unroll
      for (int qq=0;qq<4;qq++){
        int i = i0 + q4*4 + qq;
        float tv = tq[qq];
        #pragma unroll
        for (int o=0;o<16;o++) a_o[o] = fmaf(tv, linv[i*16+o], a_o[o]);
      }
    }
    FENCE();
  }

  // ---- vv (cols 144..159) -> tbA ; cx (cols 160..175) -> tbB ----
  mfma_tile(W2hi, W2lo, 144, bfr, wv, l, tbA);
  mfma_tile(W2hi, W2lo, 160, bfr, wv, l, tbB);
  FENCE();
  {
    float wvv[16], wcx[16];
    decode_w(tbA, t, wvv);
    decode_w(tbB, t, wcx);
    // two o-halves to cap register pressure
    #pragma unroll 1
    for (int hf=0; hf<2; ++hf){
      int ob = hf*8;
      float av[24];
      #pragma unroll
      for (int q=0;q<24;q++) av[q]=0.f;
      #pragma unroll
      for (int j4=0;j4<4;j4++){
        float4 a = vsrc4[j4*3+0];
        float4 b = vsrc4[j4*3+1];
        float4 c = vsrc4[j4*3+2];
        float vx_[4] = {a.x, a.w, b.z, c.y};
        float vy_[4] = {a.y, b.x, b.w, c.z};
        float vz_[4] = {a.z, b.y, c.x, c.w};
        #pragma unroll
        for (int jj=0;jj<4;jj++){
          int j = j4*4+jj;
          float cxv = vy_[jj]*yz - vz_[jj]*yy;
          float cyv = vz_[jj]*yx - vx_[jj]*yz;
          float czv = vx_[jj]*yy - vy_[jj]*yx;
          float w1 = wvv[j], w2 = wcx[j];
          #pragma unroll
          for (int o=0;o<8;o++){
            float t1 = w1*linv[(64+j)*16+ob+o];
            float t2 = w2*linv[(80+j)*16+ob+o];
            av[o*3+0] = fmaf(t1, vx_[jj], fmaf(t2, cxv, av[o*3+0]));
            av[o*3+1] = fmaf(t1, vy_[jj], fmaf(t2, cyv, av[o*3+1]));
            av[o*3+2] = fmaf(t1, vz_[jj], fmaf(t2, czv, av[o*3+2]));
          }
        }
      }
      #pragma unroll
      for (int o=0;o<8;o++){
        av[o*3+0] = fmaf(a_o[ob+o], yx, av[o*3+0]);
        av[o*3+1] = fmaf(a_o[ob+o], yy, av[o*3+1]);
        av[o*3+2] = fmaf(a_o[ob+o], yz, av[o*3+2]);
      }
      #pragma unroll
      for (int b2=0;b2<3;b2++){
        uint4 p;
        p.x = pack2(DEGN*av[8*b2+0], DEGN*av[8*b2+1]);
        p.y = pack2(DEGN*av[8*b2+2], DEGN*av[8*b2+3]);
        p.z = pack2(DEGN*av[8*b2+4], DEGN*av[8*b2+5]);
        p.w = pack2(DEGN*av[8*b2+6], DEGN*av[8*b2+7]);
        mrow[(10+hf*3+b2)*2] = p;
      }
    }
  }
  FENCE();

  // ---- wss tiles (cols 0..63): DIRECT consume in MFMA layout, no LDS ----
  #pragma unroll 1
  for (int st=0; st<4; ++st){
    const unsigned short* ap = W2hi + (size_t)(st*16+(l&15))*64 + ((l>>4)*8);
    const unsigned short* aq = W2lo + (size_t)(st*16+(l&15))*64 + ((l>>4)*8);
    short8 ah0 = *(const short8*)ap;
    short8 ah1 = *(const short8*)(ap+32);
    short8 al0 = *(const short8*)aq;
    short8 al1 = *(const short8*)(aq+32);
    int cb = st*16 + ((l>>4)<<2);
    #pragma unroll
    for (int ntg=0;ntg<4;ntg++){
      f32x4 acc = {0.f,0.f,0.f,0.f};
      acc = __builtin_amdgcn_mfma_f32_16x16x32_bf16(ah0, bfr[ntg][0], acc, 0,0,0);
      acc = __builtin_amdgcn_mfma_f32_16x16x32_bf16(ah1, bfr[ntg][1], acc, 0,0,0);
      acc = __builtin_amdgcn_mfma_f32_16x16x32_bf16(al0, bfr[ntg][0], acc, 0,0,0);
      acc = __builtin_amdgcn_mfma_f32_16x16x32_bf16(al1, bfr[ntg][1], acc, 0,0,0);
      int j2 = ntg*16 + (l&15);
      int src2 = __shfl(src, j2);
      float4 s4 = *(const float4*)(s + (size_t)src2*64 + cb);
      uint2 o2;
      o2.x = pack2(DEGN*acc[0]*s4.x, DEGN*acc[1]*s4.y);
      o2.y = pack2(DEGN*acc[2]*s4.z, DEGN*acc[3]*s4.w);
      int ke2 = blockIdx.x*256 + wv*64 + j2;
      unsigned* mb = (unsigned*)(msg4 + ((size_t)(ke2>>1))*32 + (cb>>3)*2 + (ke2&1));
      *(uint2*)(mb + ((cb>>2)&1)*2) = o2;
    }
    FENCE();
  }

  // ---- wvs tile (cols 64..79): DIRECT consume. m_s[64+j] = DEGN*W*(v[j].y) ----
  {
    const unsigned short* ap = W2hi + (size_t)(64+(l&15))*64 + ((l>>4)*8);
    const unsigned short* aq = W2lo + (size_t)(64+(l&15))*64 + ((l>>4)*8);
    short8 ah0 = *(const short8*)ap;
    short8 ah1 = *(const short8*)(ap+32);
    short8 al0 = *(const short8*)aq;
    short8 al1 = *(const short8*)(aq+32);
    int jb = (l>>4)<<2;   // v-channel base 0/4/8/12
    #pragma unroll
    for (int ntg=0;ntg<4;ntg++){
      f32x4 acc = {0.f,0.f,0.f,0.f};
      acc = __builtin_amdgcn_mfma_f32_16x16x32_bf16(ah0, bfr[ntg][0], acc, 0,0,0);
      acc = __builtin_amdgcn_mfma_f32_16x16x32_bf16(ah1, bfr[ntg][1], acc, 0,0,0);
      acc = __builtin_amdgcn_mfma_f32_16x16x32_bf16(al0, bfr[ntg][0], acc, 0,0,0);
      acc = __builtin_amdgcn_mfma_f32_16x16x32_bf16(al1, bfr[ntg][1], acc, 0,0,0);
      int j2 = ntg*16 + (l&15);
      int src2 = __shfl(src, j2);
      float eyx = __shfl(yx, j2), eyy = __shfl(yy, j2), eyz = __shfl(yz, j2);
      const float* vp = v + (size_t)src2*48 + jb*3;
      float4 va = *(const float4*)(vp);
      float4 vb = *(const float4*)(vp+4);
      float4 vc = *(const float4*)(vp+8);
      float d0 = va.x*eyx + va.y*eyy + va.z*eyz;
      float d1 = va.w*eyx + vb.x*eyy + vb.y*eyz;
      float d2 = vb.z*eyx + vb.w*eyy + vc.x*eyz;
      float d3 = vc.y*eyx + vc.z*eyy + vc.w*eyz;
      uint2 o2;
      o2.x = pack2(DEGN*acc[0]*d0, DEGN*acc[1]*d1);
      o2.y = pack2(DEGN*acc[2]*d2, DEGN*acc[3]*d3);
      int ke2 = blockIdx.x*256 + wv*64 + j2;
      int i64 = 64 + jb;
      unsigned* mb = (unsigned*)(msg4 + ((size_t)(ke2>>1))*32 + (i64>>3)*2 + (ke2&1));
      *(uint2*)(mb + ((i64>>2)&1)*2) = o2;
    }
  }
}

// ==================== gather: dst-CSR over src-ordered msg rows ====================
__global__ __launch_bounds__(256) void gather_nodes(
    const uint4* __restrict__ msg4,
    const int* __restrict__ off,
    const int* __restrict__ gidx,
    float* __restrict__ agg)            // [N][128] f32
{
  int tid = threadIdx.x;
  int n = blockIdx.x*16 + (tid >> 4);
  int l = tid & 15;
  if (n >= N_NODES) return;
  float acc[8];
  #pragma unroll
  for (int q=0;q<8;q++) acc[q]=0.f;
  int k1 = off[n+1];
  for (int k=off[n]; k<k1; k++){
    int m = gidx[k];
    uint4 mm = msg4[((size_t)(m>>1))*32 + l*2 + (m&1)];
    acc[0] += bflo(mm.x); acc[1] += bfhi(mm.x);
    acc[2] += bflo(mm.y); acc[3] += bfhi(mm.y);
    acc[4] += bflo(mm.z); acc[5] += bfhi(mm.z);
    acc[6] += bflo(mm.w); acc[7] += bfhi(mm.w);
  }
  float4* o = (float4*)(agg + (size_t)n*128 + l*8);
  o[0] = make_float4(acc[0],acc[1],acc[2],acc[3]);
  o[1] = make_float4(acc[4],acc[5],acc[6],acc[7]);
}

// ==================== node update ====================
__global__ __launch_bounds__(256) void node_update(
    const float* __restrict__ agg,      // [N][128]
    const float* __restrict__ lin_s, const float* __restrict__ gate_w,
    float* __restrict__ s, float* __restrict__ v)
{
  int n = blockIdx.x*256 + threadIdx.x;
  if (n >= N_NODES) return;
  const float* row = agg + (size_t)n*128;
  float outs[64];
  #pragma unroll
  for (int o=0;o<64;o++) outs[o]=0.f;
  for (int i=0;i<80;i+=4){
    float4 a4 = *(const float4*)(row + i);
    float av[4]={a4.x,a4.y,a4.z,a4.w};
    #pragma unroll
    for (int q=0;q<4;q++){
      float a = av[q];
      #pragma unroll
      for (int o=0;o<64;o++) outs[o] = fmaf(a, lin_s[(i+q)*64+o], outs[o]);
    }
  }
  float g[16];
  #pragma unroll
  for (int j=0;j<16;j++) g[j]=0.f;
  for (int o=0;o<64;o++){
    float x = outs[o];
    #pragma unroll
    for (int j=0;j<16;j++) g[j] = fmaf(x, gate_w[o*16+j], g[j]);
    s[(size_t)n*64+o] += fsilu(x);
  }
  #pragma unroll
  for (int j=0;j<16;j++){
    float gv = fsig(g[j]);
    v[(size_t)n*48+j*3+0] += row[80+j*3+0]*gv;
    v[(size_t)n*48+j*3+1] += row[80+j*3+1]*gv;
    v[(size_t)n*48+j*3+2] += row[80+j*3+2]*gv;
  }
}

// ==================== output head ====================
__global__ __launch_bounds__(256) void head_kernel(
    const float* __restrict__ s, const float* __restrict__ v,
    const float* __restrict__ hs1, const float* __restrict__ hg,
    const float* __restrict__ hs2, const float* __restrict__ hv2,
    float* __restrict__ out)
{
  int n = blockIdx.x*256 + threadIdx.x;
  if (n >= N_NODES) return;
  float sv[64];
  const float4* sp = (const float4*)(s + (size_t)n*64);
  #pragma unroll
  for (int q=0;q<16;q++){ float4 t=sp[q]; sv[4*q]=t.x; sv[4*q+1]=t.y; sv[4*q+2]=t.z; sv[4*q+3]=t.w; }
  float h[64];
  #pragma unroll
  for (int o=0;o<64;o++) h[o]=0.f;
  for (int k=0;k<64;k++){
    float x = sv[k];
    #pragma unroll
    for (int o=0;o<64;o++) h[o] = fmaf(x, hs1[k*64+o], h[o]);
  }
  #pragma unroll
  for (int o=0;o<64;o++) h[o] = fsilu(h[o]);
  float g[16];
  #pragma unroll
  for (int j=0;j<16;j++) g[j]=0.f;
  float ps = 0.f;
  for (int o=0;o<64;o++){
    float x = h[o];
    #pragma unroll
    for (int j=0;j<16;j++) g[j] = fmaf(x, hg[o*16+j], g[j]);
    ps = fmaf(x, hs2[o], ps);
  }
  float pvx=0.f, pvy=0.f, pvz=0.f;
  #pragma unroll
  for (int j=0;j<16;j++){
    float gv = fsig(g[j]) * hv2[j];
    pvx = fmaf(v[(size_t)n*48+j*3+0], gv, pvx);
    pvy = fmaf(v[(size_t)n*48+j*3+1], gv, pvy);
    pvz = fmaf(v[(size_t)n*48+j*3+2], gv, pvz);
  }
  *(float4*)(out + (size_t)n*4) = make_float4(ps, pvx, pvy, pvz);
}

extern "C" void kernel_launch(void* const* d_in, const int* in_sizes, int n_in,
                              void* d_out, int out_size, void* d_ws, size_t ws_size,
                              hipStream_t stream)
{
  const float* pos       = (const float*)d_in[0];
  const int*   ei        = (const int*)  d_in[1];
  const int*   bond_mask = (const int*)  d_in[2];
  const int*   atom_type = (const int*)  d_in[3];
  const float* atom_emb  = (const float*)d_in[4];
  const float* bond_emb  = (const float*)d_in[5];
  const float* w_init    = (const float*)d_in[6];
  const float* mlp_w1    = (const float*)d_in[7];
  const float* mlp_b1    = (const float*)d_in[8];
  const float* mlp_w2    = (const float*)d_in[9];
  const float* lin_s     = (const float*)d_in[10];
  const float* lin_v     = (const float*)d_in[11];
  const float* gate_w    = (const float*)d_in[12];
  const float* hs1       = (const float*)d_in[13];
  const float* hg        = (const float*)d_in[14];
  const float* hs2       = (const float*)d_in[15];
  const float* hv2       = (const float*)d_in[16];
  float* out = (float*)d_out;

  char* ws = (char*)d_ws;
  size_t off_b = 0;
  auto alloc = [&](size_t nbytes){ void* p = (void*)(ws + off_b); off_b += ((nbytes + 255)/256)*256; return p; };
  uint4*    rec     = (uint4*)   alloc((size_t)N_EDGES*48);
  uint4*    msg4    = (uint4*)   alloc((size_t)N_EDGES*256);
  float*    sbuf    = (float*)   alloc((size_t)N_NODES*64*4);
  float*    vbuf    = (float*)   alloc((size_t)N_NODES*48*4);
  float*    agg     = (float*)   alloc((size_t)N_NODES*128*4);
  unsigned short* w2hi = (unsigned short*)alloc((size_t)3*176*64*2);
  unsigned short* w2lo = (unsigned short*)alloc((size_t)3*176*64*2);
  int*      deg_src = (int*)     alloc((size_t)N_NODES*4);   // contiguous with deg_dst -> one memset
  int*      deg_dst = (int*)     alloc((size_t)N_NODES*4);
  int*      off_src = (int*)     alloc((size_t)(N_NODES+1)*4);
  int*      off_dst = (int*)     alloc((size_t)(N_NODES+1)*4);
  int*      cur_src = (int*)     alloc((size_t)N_NODES*4);
  int*      cur_dst = (int*)     alloc((size_t)N_NODES*4);
  int*      csr_src = (int*)     alloc((size_t)N_EDGES*4);
  int*      pos_src = (int*)     alloc((size_t)N_EDGES*4);
  int*      gidx    = (int*)     alloc((size_t)N_EDGES*4);

  dim3 blk(256);
  int gE = (N_EDGES + 255)/256;
  int gN = (N_NODES + 255)/256;
  int gG = (N_NODES + 15)/16;

  hipMemsetAsync(vbuf, 0, (size_t)N_NODES*48*sizeof(float), stream);
  hipMemsetAsync(deg_src, 0, (size_t)2*N_NODES*sizeof(int) + 512, stream);

  count2<<<gE, blk, 0, stream>>>(ei, deg_src, deg_dst);
  scan_deg2<<<2, 1024, 0, stream>>>(deg_src, off_src, cur_src, deg_dst, off_dst, cur_dst);
  scatter_src<<<gE, blk, 0, stream>>>(ei, cur_src, csr_src, pos_src);
  scatter_dst<<<gE, blk, 0, stream>>>(ei, pos_src, cur_dst, gidx);

  prep_edges2<<<gE, blk, 0, stream>>>(pos, ei, bond_mask, bond_emb, csr_src, rec);
  prep_weights<<<(3*176*64 + 255)/256, blk, 0, stream>>>(mlp_w2, w2hi, w2lo);
  init_nodes<<<gN, blk, 0, stream>>>(atom_type, atom_emb, w_init, sbuf);

  for (int l=0;l<3;l++){
    edge_fused2<<<NBLK, blk, 0, stream>>>(rec, sbuf, vbuf,
        mlp_w1 + (size_t)l*16*64, mlp_b1 + (size_t)l*64,
        w2hi + (size_t)l*176*64, w2lo + (size_t)l*176*64,
        lin_v + (size_t)l*96*16,
        msg4);
    gather_nodes<<<gG, blk, 0, stream>>>(msg4, off_dst, gidx, agg);
    node_update<<<gN, blk, 0, stream>>>(agg,
        lin_s + (size_t)l*80*64, gate_w + (size_t)l*64*16, sbuf, vbuf);
  }
  head_kernel<<<gN, blk, 0, stream>>>(sbuf, vbuf, hs1, hg, hs2, hv2, out);
}

// Round 17
// 1188.847 us; speedup vs baseline: 1.2272x; 1.2272x over previous
//
#include <hip/hip_runtime.h>
#include <math.h>

#define N_NODES 30000
#define N_EDGES 480000
#define DEGN 0.25f   // 1/sqrt(16)
#define NBLK 1875    // N_EDGES/256
#define TPITCH 52    // odd dword stride -> conflict-free (verified: 1.32M -> 0)

// Phase fence: stops IR motion + backend scheduling across phase boundaries
// (round-9 lesson: unrestricted motion -> live-range blowup -> 2 GB spill).
#define FENCE() do { asm volatile("" ::: "memory"); __builtin_amdgcn_sched_barrier(0); } while(0)

typedef __attribute__((ext_vector_type(8))) short short8;
typedef __attribute__((ext_vector_type(4))) float f32x4;

__device__ __forceinline__ float fsilu(float x){ return x / (1.f + __expf(-x)); }
__device__ __forceinline__ float fsig (float x){ return 1.f / (1.f + __expf(-x)); }

__device__ __forceinline__ unsigned bf16rn(float x){
  unsigned u = __float_as_uint(x);
  return (u + 0x7fffu + ((u>>16)&1u)) >> 16;
}
__device__ __forceinline__ unsigned pack2(float a, float b){
  return bf16rn(a) | (bf16rn(b)<<16);
}
__device__ __forceinline__ float bflo(unsigned u){ return __uint_as_float(u<<16); }
__device__ __forceinline__ float bfhi(unsigned u){ return __uint_as_float(u & 0xffff0000u); }

// ==================== degree counts (src and dst) ====================
__global__ __launch_bounds__(256) void count2(const int* __restrict__ ei,
                                              int* __restrict__ deg_src,
                                              int* __restrict__ deg_dst)
{
  int e = blockIdx.x*256 + threadIdx.x;
  if (e >= N_EDGES) return;
  atomicAdd(deg_src + ei[e], 1);
  atomicAdd(deg_dst + ei[N_EDGES + e], 1);
}

// 2 blocks: block 0 scans src arrays, block 1 scans dst arrays
__global__ __launch_bounds__(1024) void scan_deg2(
    const int* __restrict__ deg_src, int* __restrict__ off_src, int* __restrict__ cur_src,
    const int* __restrict__ deg_dst, int* __restrict__ off_dst, int* __restrict__ cur_dst)
{
  const int* deg = blockIdx.x ? deg_dst : deg_src;
  int* off = blockIdx.x ? off_dst : off_src;
  int* cur = blockIdx.x ? cur_dst : cur_src;
  __shared__ int part[1024];
  int t = threadIdx.x;
  int base = t*30;
  int local[30];
  int s = 0;
  #pragma unroll
  for (int i=0;i<30;i++){
    int idx = base + i;
    int d = (idx < N_NODES) ? deg[idx] : 0;
    local[i] = s; s += d;
  }
  part[t] = s; __syncthreads();
  for (int stp=1; stp<1024; stp<<=1){
    int v = (t >= stp) ? part[t-stp] : 0;
    __syncthreads();
    part[t] += v;
    __syncthreads();
  }
  int prefix = (t==0) ? 0 : part[t-1];
  #pragma unroll
  for (int i=0;i<30;i++){
    int idx = base + i;
    if (idx < N_NODES){ int o = prefix + local[i]; off[idx] = o; cur[idx] = o; }
  }
  if (t == 1023) off[N_NODES] = part[1023];
}

// src-order scatter: csr_src[m]=e, pos_src[e]=m
__global__ __launch_bounds__(256) void scatter_src(const int* __restrict__ ei,
                                                   int* __restrict__ cur,
                                                   int* __restrict__ csr_src,
                                                   int* __restrict__ pos_src)
{
  int e = blockIdx.x*256 + threadIdx.x;
  if (e >= N_EDGES) return;
  int p = atomicAdd(cur + ei[e], 1);
  csr_src[p] = e;
  pos_src[e] = p;
}

// dst-order scatter of src-positions: gidx[k] = pos_src[e]
__global__ __launch_bounds__(256) void scatter_dst(const int* __restrict__ ei,
                                                   const int* __restrict__ pos_src,
                                                   int* __restrict__ cur,
                                                   int* __restrict__ gidx)
{
  int e = blockIdx.x*256 + threadIdx.x;
  if (e >= N_EDGES) return;
  int p = atomicAdd(cur + ei[N_EDGES + e], 1);
  gidx[p] = pos_src[e];
}

// ==================== per-edge record in SRC order ====================
// rec[k] = 48 B: 8 u32 (16 bf16 ea) | y1x,y1y,y1z f32 | src int
__global__ __launch_bounds__(256) void prep_edges2(
    const float* __restrict__ pos, const int* __restrict__ ei,
    const int* __restrict__ bond_mask, const float* __restrict__ bond_emb,
    const int* __restrict__ csr_src, uint4* __restrict__ rec)
{
  int k = blockIdx.x*256 + threadIdx.x;
  if (k >= N_EDGES) return;
  int e = csr_src[k];
  int src = ei[e], dst = ei[N_EDGES + e];
  float ax = pos[src*3+0], ay = pos[src*3+1], az = pos[src*3+2];
  float bx = pos[dst*3+0], by = pos[dst*3+1], bz = pos[dst*3+2];
  float vx = ax-bx, vy = ay-by, vz = az-bz;
  float r = sqrtf(vx*vx + vy*vy + vz*vz);
  float inv = 1.f / fmaxf(r, 1e-9f);
  const float s3 = 1.7320508075688772f;
  float yx = s3*vx*inv, yy = s3*vy*inv, yz = s3*vz*inv;
  int bm = bond_mask[e];
  float eav[16];
  #pragma unroll
  for (int q=0;q<8;q++) eav[q] = bond_emb[bm*8+q];
  const float step = 5.0f/9.0f;
  #pragma unroll
  for (int j=0;j<8;j++){
    float vj = (float)(j+1)*step;
    float d = (r - vj)/step;
    eav[8+j] = __expf(-d*d) * (1.0f/1.12f);
  }
  uint4 r0, r1, r2;
  r0.x = pack2(eav[0],eav[1]);  r0.y = pack2(eav[2],eav[3]);
  r0.z = pack2(eav[4],eav[5]);  r0.w = pack2(eav[6],eav[7]);
  r1.x = pack2(eav[8],eav[9]);  r1.y = pack2(eav[10],eav[11]);
  r1.z = pack2(eav[12],eav[13]);r1.w = pack2(eav[14],eav[15]);
  r2.x = __float_as_uint(yx); r2.y = __float_as_uint(yy);
  r2.z = __float_as_uint(yz); r2.w = (unsigned)src;
  rec[(size_t)k*3+0] = r0;
  rec[(size_t)k*3+1] = r1;
  rec[(size_t)k*3+2] = r2;
}

// ==================== W2 -> bf16 hi/lo, [176][64] ====================
__global__ void prep_weights(const float* __restrict__ w2,
                             unsigned short* __restrict__ w2hi,
                             unsigned short* __restrict__ w2lo)
{
  int i = blockIdx.x*256 + threadIdx.x;
  if (i >= 3*176*64) return;
  int l = i / (176*64); int rem = i - l*(176*64);
  int n = rem / 64, k = rem - n*64;
  float w = w2[(size_t)l*64*176 + (size_t)k*176 + n];
  unsigned hi = bf16rn(w);
  float lo = w - __uint_as_float(hi<<16);
  w2hi[i] = (unsigned short)hi;
  w2lo[i] = (unsigned short)bf16rn(lo);
}

// ==================== init s ====================
__global__ __launch_bounds__(256) void init_nodes(
    const int* __restrict__ atom_type, const float* __restrict__ atom_emb,
    const float* __restrict__ w_init, float* __restrict__ s)
{
  int n = blockIdx.x*256 + threadIdx.x;
  if (n >= N_NODES) return;
  int t = atom_type[n];
  float acc[64];
  #pragma unroll
  for (int o=0;o<64;o++) acc[o]=0.f;
  for (int k=0;k<64;k++){
    float ek = atom_emb[t*64+k];
    #pragma unroll
    for (int o=0;o<64;o++) acc[o] = fmaf(ek, w_init[k*64+o], acc[o]);
  }
  float4* so = (float4*)(s + (size_t)n*64);
  #pragma unroll
  for (int q=0;q<16;q++) so[q] = make_float4(acc[4*q],acc[4*q+1],acc[4*q+2],acc[4*q+3]);
}

// ==================== fused edge kernel (round 17) ====================
// Round-13 base (verified 292 us: disjoint LDS, barrier-free, TPITCH 52,
// no occupancy hints -> VGPR 256, zero spill) + tile PAIRING for ILP:
// two independent tiles per fence region (sv: 4 regions -> 2; wss: 4 -> 2).
// Loop body doubles, trip count halves -> same I-cache footprint (the
// round-12 full-unroll failure mode is avoided). Occupancy path abandoned:
// HW VGPR ladder has no 3-wave step (r16: VGPR=168 -> still 2 waves/SIMD).
__device__ __forceinline__ void mfma_tile(
    const unsigned short* __restrict__ W2hi, const unsigned short* __restrict__ W2lo,
    int colbase, const short8 (&bfr)[4][2], int wv, int l, unsigned char* tb)
{
  const unsigned short* ap = W2hi + (size_t)(colbase+(l&15))*64 + ((l>>4)*8);
  const unsigned short* aq = W2lo + (size_t)(colbase+(l&15))*64 + ((l>>4)*8);
  short8 ah0 = *(const short8*)ap;
  short8 ah1 = *(const short8*)(ap+32);
  short8 al0 = *(const short8*)aq;
  short8 al1 = *(const short8*)(aq+32);
  #pragma unroll
  for (int ntg=0;ntg<4;ntg++){
    f32x4 acc = {0.f,0.f,0.f,0.f};
    acc = __builtin_amdgcn_mfma_f32_16x16x32_bf16(ah0, bfr[ntg][0], acc, 0,0,0);
    acc = __builtin_amdgcn_mfma_f32_16x16x32_bf16(ah1, bfr[ntg][1], acc, 0,0,0);
    acc = __builtin_amdgcn_mfma_f32_16x16x32_bf16(al0, bfr[ntg][0], acc, 0,0,0);
    acc = __builtin_amdgcn_mfma_f32_16x16x32_bf16(al1, bfr[ntg][1], acc, 0,0,0);
    int e = wv*64 + ntg*16 + (l&15);
    uint2 pk; pk.x = pack2(acc[0],acc[1]); pk.y = pack2(acc[2],acc[3]);
    *(uint2*)(tb + (size_t)e*TPITCH + ((l>>4)*8)) = pk;
  }
}

__device__ __forceinline__ void decode_w(const unsigned char* tb, int t, float* w)
{
  const unsigned char* wr = tb + (size_t)t*TPITCH;
  uint4 c0 = *(const uint4*)wr;
  uint4 c1 = *(const uint4*)(wr+16);
  w[0]=bflo(c0.x); w[1]=bfhi(c0.x); w[2]=bflo(c0.y); w[3]=bfhi(c0.y);
  w[4]=bflo(c0.z); w[5]=bfhi(c0.z); w[6]=bflo(c0.w); w[7]=bfhi(c0.w);
  w[8]=bflo(c1.x); w[9]=bfhi(c1.x); w[10]=bflo(c1.y); w[11]=bfhi(c1.y);
  w[12]=bflo(c1.z); w[13]=bfhi(c1.z); w[14]=bflo(c1.w); w[15]=bfhi(c1.w);
}

__device__ __forceinline__ void consume_sv(const float* w, int i0,
    const float* __restrict__ ssrc, const float* __restrict__ linv, float* a_o)
{
  #pragma unroll
  for (int q4=0;q4<4;q4++){
    float4 s4 = *(const float4*)(ssrc + i0 + q4*4);
    float tq[4] = { w[q4*4+0]*s4.x, w[q4*4+1]*s4.y, w[q4*4+2]*s4.z, w[q4*4+3]*s4.w };
    #pragma unroll
    for (int qq=0;qq<4;qq++){
      int i = i0 + q4*4 + qq;
      float tv = tq[qq];
      #pragma unroll
      for (int o=0;o<16;o++) a_o[o] = fmaf(tv, linv[i*16+o], a_o[o]);
    }
  }
}

// direct wss tile: MFMA C-layout consume (elementwise in col), no LDS
__device__ __forceinline__ void direct_wss(
    const unsigned short* __restrict__ W2hi, const unsigned short* __restrict__ W2lo,
    int colbase, const short8 (&bfr)[4][2], int wv, int l, int src,
    const float* __restrict__ s, uint4* __restrict__ msg4, int kb0)
{
  const unsigned short* ap = W2hi + (size_t)(colbase+(l&15))*64 + ((l>>4)*8);
  const unsigned short* aq = W2lo + (size_t)(colbase+(l&15))*64 + ((l>>4)*8);
  short8 ah0 = *(const short8*)ap;
  short8 ah1 = *(const short8*)(ap+32);
  short8 al0 = *(const short8*)aq;
  short8 al1 = *(const short8*)(aq+32);
  int cb = colbase + ((l>>4)<<2);
  #pragma unroll
  for (int ntg=0;ntg<4;ntg++){
    f32x4 acc = {0.f,0.f,0.f,0.f};
    acc = __builtin_amdgcn_mfma_f32_16x16x32_bf16(ah0, bfr[ntg][0], acc, 0,0,0);
    acc = __builtin_amdgcn_mfma_f32_16x16x32_bf16(ah1, bfr[ntg][1], acc, 0,0,0);
    acc = __builtin_amdgcn_mfma_f32_16x16x32_bf16(al0, bfr[ntg][0], acc, 0,0,0);
    acc = __builtin_amdgcn_mfma_f32_16x16x32_bf16(al1, bfr[ntg][1], acc, 0,0,0);
    int j2 = ntg*16 + (l&15);
    int src2 = __shfl(src, j2);
    float4 s4 = *(const float4*)(s + (size_t)src2*64 + cb);
    uint2 o2;
    o2.x = pack2(DEGN*acc[0]*s4.x, DEGN*acc[1]*s4.y);
    o2.y = pack2(DEGN*acc[2]*s4.z, DEGN*acc[3]*s4.w);
    int ke2 = kb0 + wv*64 + j2;
    unsigned* mb = (unsigned*)(msg4 + ((size_t)(ke2>>1))*32 + (cb>>3)*2 + (ke2&1));
    *(uint2*)(mb + ((cb>>2)&1)*2) = o2;
  }
}

__global__ __launch_bounds__(256)
void edge_fused2(
    const uint4* __restrict__ rec,
    const float* __restrict__ s, const float* __restrict__ v,
    const float* __restrict__ W1,      // [16][64] f32
    const float* __restrict__ b1,      // [64] f32
    const unsigned short* __restrict__ W2hi, // [176][64] bf16
    const unsigned short* __restrict__ W2lo, // [176][64] bf16
    const float* __restrict__ linv,    // [96][16] f32
    uint4* __restrict__ msg4)          // pair-interleaved, src-order index
{
  // H: [0,32768). tbA: [32768,46080). tbB: [46080,59392). Disjoint, wave-local rows.
  __shared__ __align__(16) unsigned char lds[59392];
  int t = threadIdx.x;
  int ke = blockIdx.x*256 + t;

  uint4 r0 = rec[(size_t)ke*3+0];
  uint4 r1 = rec[(size_t)ke*3+1];
  uint4 r2 = rec[(size_t)ke*3+2];
  float yx = __uint_as_float(r2.x), yy = __uint_as_float(r2.y), yz = __uint_as_float(r2.z);
  int src = (int)r2.w;

  // ---- phase H: h = silu(ea@W1+b1) -> LDS (swizzled, own row) ----
  {
    float eav[16];
    eav[0]=bflo(r0.x); eav[1]=bfhi(r0.x); eav[2]=bflo(r0.y); eav[3]=bfhi(r0.y);
    eav[4]=bflo(r0.z); eav[5]=bfhi(r0.z); eav[6]=bflo(r0.w); eav[7]=bfhi(r0.w);
    eav[8]=bflo(r1.x); eav[9]=bfhi(r1.x); eav[10]=bflo(r1.y); eav[11]=bfhi(r1.y);
    eav[12]=bflo(r1.z); eav[13]=bfhi(r1.z); eav[14]=bflo(r1.w); eav[15]=bfhi(r1.w);
    float h[64];
    #pragma unroll
    for (int k=0;k<64;k++) h[k] = b1[k];
    #pragma unroll
    for (int j=0;j<16;j++){
      float a = eav[j];
      #pragma unroll
      for (int k=0;k<64;k++) h[k] = fmaf(a, W1[j*64+k], h[k]);
    }
    #pragma unroll
    for (int k=0;k<64;k++) h[k] = fsilu(h[k]);
    #pragma unroll
    for (int q=0;q<8;q++){
      uint4 hp;
      hp.x = pack2(h[8*q+0],h[8*q+1]); hp.y = pack2(h[8*q+2],h[8*q+3]);
      hp.z = pack2(h[8*q+4],h[8*q+5]); hp.w = pack2(h[8*q+6],h[8*q+7]);
      int byte = (t*128 + q*16) ^ ((t&7)<<4);
      *(uint4*)(lds + byte) = hp;
    }
  }
  FENCE();

  // ---- B-fragments (H rows = this wave's own 64 edges) ----
  int wv = t>>6, l = t&63;
  short8 bfr[4][2];
  #pragma unroll
  for (int ntg=0;ntg<4;ntg++){
    int erow = wv*64 + ntg*16 + (l&15);
    #pragma unroll
    for (int kk=0;kk<2;kk++){
      int byte = (erow*128 + kk*64 + ((l>>4)*16)) ^ ((erow&7)<<4);
      bfr[ntg][kk] = *(const short8*)(lds + byte);
    }
  }
  FENCE();

  unsigned char* tbA = lds + 32768;
  unsigned char* tbB = lds + 46080;
  const float* ssrc = s + (size_t)src*64;
  const float4* vsrc4 = (const float4*)(v + (size_t)src*48);
  uint4* mrow = msg4 + ((size_t)(ke>>1))*32 + (ke&1);

  // ---- sv tiles (cols 80..143): build a_o -- PAIRED (2 tiles/region) ----
  float a_o[16];
  #pragma unroll
  for (int o=0;o<16;o++) a_o[o]=0.f;
  #pragma unroll 1
  for (int st=0; st<2; ++st){
    mfma_tile(W2hi, W2lo, 80+st*32,    bfr, wv, l, tbA);
    mfma_tile(W2hi, W2lo, 80+st*32+16, bfr, wv, l, tbB);
    FENCE();
    float wa[16], wb[16];
    decode_w(tbA, t, wa);
    decode_w(tbB, t, wb);
    consume_sv(wa, st*32,    ssrc, linv, a_o);
    consume_sv(wb, st*32+16, ssrc, linv, a_o);
    FENCE();
  }

  // ---- vv (cols 144..159) -> tbA ; cx (cols 160..175) -> tbB ----
  mfma_tile(W2hi, W2lo, 144, bfr, wv, l, tbA);
  mfma_tile(W2hi, W2lo, 160, bfr, wv, l, tbB);
  FENCE();
  {
    float wvv[16], wcx[16];
    decode_w(tbA, t, wvv);
    decode_w(tbB, t, wcx);
    // two o-halves to cap register pressure
    #pragma unroll 1
    for (int hf=0; hf<2; ++hf){
      int ob = hf*8;
      float av[24];
      #pragma unroll
      for (int q=0;q<24;q++) av[q]=0.f;
      #pragma unroll
      for (int j4=0;j4<4;j4++){
        float4 a = vsrc4[j4*3+0];
        float4 b = vsrc4[j4*3+1];
        float4 c = vsrc4[j4*3+2];
        float vx_[4] = {a.x, a.w, b.z, c.y};
        float vy_[4] = {a.y, b.x, b.w, c.z};
        float vz_[4] = {a.z, b.y, c.x, c.w};
        #pragma unroll
        for (int jj=0;jj<4;jj++){
          int j = j4*4+jj;
          float cxv = vy_[jj]*yz - vz_[jj]*yy;
          float cyv = vz_[jj]*yx - vx_[jj]*yz;
          float czv = vx_[jj]*yy - vy_[jj]*yx;
          float w1 = wvv[j], w2 = wcx[j];
          #pragma unroll
          for (int o=0;o<8;o++){
            float t1 = w1*linv[(64+j)*16+ob+o];
            float t2 = w2*linv[(80+j)*16+ob+o];
            av[o*3+0] = fmaf(t1, vx_[jj], fmaf(t2, cxv, av[o*3+0]));
            av[o*3+1] = fmaf(t1, vy_[jj], fmaf(t2, cyv, av[o*3+1]));
            av[o*3+2] = fmaf(t1, vz_[jj], fmaf(t2, czv, av[o*3+2]));
          }
        }
      }
      #pragma unroll
      for (int o=0;o<8;o++){
        av[o*3+0] = fmaf(a_o[ob+o], yx, av[o*3+0]);
        av[o*3+1] = fmaf(a_o[ob+o], yy, av[o*3+1]);
        av[o*3+2] = fmaf(a_o[ob+o], yz, av[o*3+2]);
      }
      #pragma unroll
      for (int b2=0;b2<3;b2++){
        uint4 p;
        p.x = pack2(DEGN*av[8*b2+0], DEGN*av[8*b2+1]);
        p.y = pack2(DEGN*av[8*b2+2], DEGN*av[8*b2+3]);
        p.z = pack2(DEGN*av[8*b2+4], DEGN*av[8*b2+5]);
        p.w = pack2(DEGN*av[8*b2+6], DEGN*av[8*b2+7]);
        mrow[(10+hf*3+b2)*2] = p;
      }
    }
  }
  FENCE();

  // ---- wss tiles (cols 0..63): DIRECT consume -- PAIRED (2 tiles/region) ----
  int kb0 = blockIdx.x*256;
  #pragma unroll 1
  for (int st=0; st<2; ++st){
    direct_wss(W2hi, W2lo, st*32,    bfr, wv, l, src, s, msg4, kb0);
    direct_wss(W2hi, W2lo, st*32+16, bfr, wv, l, src, s, msg4, kb0);
    FENCE();
  }

  // ---- wvs tile (cols 64..79): DIRECT consume. m_s[64+j] = DEGN*W*(v[j].y) ----
  {
    const unsigned short* ap = W2hi + (size_t)(64+(l&15))*64 + ((l>>4)*8);
    const unsigned short* aq = W2lo + (size_t)(64+(l&15))*64 + ((l>>4)*8);
    short8 ah0 = *(const short8*)ap;
    short8 ah1 = *(const short8*)(ap+32);
    short8 al0 = *(const short8*)aq;
    short8 al1 = *(const short8*)(aq+32);
    int jb = (l>>4)<<2;   // v-channel base 0/4/8/12
    #pragma unroll
    for (int ntg=0;ntg<4;ntg++){
      f32x4 acc = {0.f,0.f,0.f,0.f};
      acc = __builtin_amdgcn_mfma_f32_16x16x32_bf16(ah0, bfr[ntg][0], acc, 0,0,0);
      acc = __builtin_amdgcn_mfma_f32_16x16x32_bf16(ah1, bfr[ntg][1], acc, 0,0,0);
      acc = __builtin_amdgcn_mfma_f32_16x16x32_bf16(al0, bfr[ntg][0], acc, 0,0,0);
      acc = __builtin_amdgcn_mfma_f32_16x16x32_bf16(al1, bfr[ntg][1], acc, 0,0,0);
      int j2 = ntg*16 + (l&15);
      int src2 = __shfl(src, j2);
      float eyx = __shfl(yx, j2), eyy = __shfl(yy, j2), eyz = __shfl(yz, j2);
      const float* vp = v + (size_t)src2*48 + jb*3;
      float4 va = *(const float4*)(vp);
      float4 vb = *(const float4*)(vp+4);
      float4 vc = *(const float4*)(vp+8);
      float d0 = va.x*eyx + va.y*eyy + va.z*eyz;
      float d1 = va.w*eyx + vb.x*eyy + vb.y*eyz;
      float d2 = vb.z*eyx + vb.w*eyy + vc.x*eyz;
      float d3 = vc.y*eyx + vc.z*eyy + vc.w*eyz;
      uint2 o2;
      o2.x = pack2(DEGN*acc[0]*d0, DEGN*acc[1]*d1);
      o2.y = pack2(DEGN*acc[2]*d2, DEGN*acc[3]*d3);
      int ke2 = kb0 + wv*64 + j2;
      int i64 = 64 + jb;
      unsigned* mb = (unsigned*)(msg4 + ((size_t)(ke2>>1))*32 + (i64>>3)*2 + (ke2&1));
      *(uint2*)(mb + ((i64>>2)&1)*2) = o2;
    }
  }
}

// ==================== gather: dst-CSR over src-ordered msg rows ====================
__global__ __launch_bounds__(256) void gather_nodes(
    const uint4* __restrict__ msg4,
    const int* __restrict__ off,
    const int* __restrict__ gidx,
    float* __restrict__ agg)            // [N][128] f32
{
  int tid = threadIdx.x;
  int n = blockIdx.x*16 + (tid >> 4);
  int l = tid & 15;
  if (n >= N_NODES) return;
  float acc[8];
  #pragma unroll
  for (int q=0;q<8;q++) acc[q]=0.f;
  int k1 = off[n+1];
  for (int k=off[n]; k<k1; k++){
    int m = gidx[k];
    uint4 mm = msg4[((size_t)(m>>1))*32 + l*2 + (m&1)];
    acc[0] += bflo(mm.x); acc[1] += bfhi(mm.x);
    acc[2] += bflo(mm.y); acc[3] += bfhi(mm.y);
    acc[4] += bflo(mm.z); acc[5] += bfhi(mm.z);
    acc[6] += bflo(mm.w); acc[7] += bfhi(mm.w);
  }
  float4* o = (float4*)(agg + (size_t)n*128 + l*8);
  o[0] = make_float4(acc[0],acc[1],acc[2],acc[3]);
  o[1] = make_float4(acc[4],acc[5],acc[6],acc[7]);
}

// ==================== node update ====================
__global__ __launch_bounds__(256) void node_update(
    const float* __restrict__ agg,      // [N][128]
    const float* __restrict__ lin_s, const float* __restrict__ gate_w,
    float* __restrict__ s, float* __restrict__ v)
{
  int n = blockIdx.x*256 + threadIdx.x;
  if (n >= N_NODES) return;
  const float* row = agg + (size_t)n*128;
  float outs[64];
  #pragma unroll
  for (int o=0;o<64;o++) outs[o]=0.f;
  for (int i=0;i<80;i+=4){
    float4 a4 = *(const float4*)(row + i);
    float av[4]={a4.x,a4.y,a4.z,a4.w};
    #pragma unroll
    for (int q=0;q<4;q++){
      float a = av[q];
      #pragma unroll
      for (int o=0;o<64;o++) outs[o] = fmaf(a, lin_s[(i+q)*64+o], outs[o]);
    }
  }
  float g[16];
  #pragma unroll
  for (int j=0;j<16;j++) g[j]=0.f;
  for (int o=0;o<64;o++){
    float x = outs[o];
    #pragma unroll
    for (int j=0;j<16;j++) g[j] = fmaf(x, gate_w[o*16+j], g[j]);
    s[(size_t)n*64+o] += fsilu(x);
  }
  #pragma unroll
  for (int j=0;j<16;j++){
    float gv = fsig(g[j]);
    v[(size_t)n*48+j*3+0] += row[80+j*3+0]*gv;
    v[(size_t)n*48+j*3+1] += row[80+j*3+1]*gv;
    v[(size_t)n*48+j*3+2] += row[80+j*3+2]*gv;
  }
}

// ==================== output head ====================
__global__ __launch_bounds__(256) void head_kernel(
    const float* __restrict__ s, const float* __restrict__ v,
    const float* __restrict__ hs1, const float* __restrict__ hg,
    const float* __restrict__ hs2, const float* __restrict__ hv2,
    float* __restrict__ out)
{
  int n = blockIdx.x*256 + threadIdx.x;
  if (n >= N_NODES) return;
  float sv[64];
  const float4* sp = (const float4*)(s + (size_t)n*64);
  #pragma unroll
  for (int q=0;q<16;q++){ float4 t=sp[q]; sv[4*q]=t.x; sv[4*q+1]=t.y; sv[4*q+2]=t.z; sv[4*q+3]=t.w; }
  float h[64];
  #pragma unroll
  for (int o=0;o<64;o++) h[o]=0.f;
  for (int k=0;k<64;k++){
    float x = sv[k];
    #pragma unroll
    for (int o=0;o<64;o++) h[o] = fmaf(x, hs1[k*64+o], h[o]);
  }
  #pragma unroll
  for (int o=0;o<64;o++) h[o] = fsilu(h[o]);
  float g[16];
  #pragma unroll
  for (int j=0;j<16;j++) g[j]=0.f;
  float ps = 0.f;
  for (int o=0;o<64;o++){
    float x = h[o];
    #pragma unroll
    for (int j=0;j<16;j++) g[j] = fmaf(x, hg[o*16+j], g[j]);
    ps = fmaf(x, hs2[o], ps);
  }
  float pvx=0.f, pvy=0.f, pvz=0.f;
  #pragma unroll
  for (int j=0;j<16;j++){
    float gv = fsig(g[j]) * hv2[j];
    pvx = fmaf(v[(size_t)n*48+j*3+0], gv, pvx);
    pvy = fmaf(v[(size_t)n*48+j*3+1], gv, pvy);
    pvz = fmaf(v[(size_t)n*48+j*3+2], gv, pvz);
  }
  *(float4*)(out + (size_t)n*4) = make_float4(ps, pvx, pvy, pvz);
}

extern "C" void kernel_launch(void* const* d_in, const int* in_sizes, int n_in,
                              void* d_out, int out_size, void* d_ws, size_t ws_size,
                              hipStream_t stream)
{
  const float* pos       = (const float*)d_in[0];
  const int*   ei        = (const int*)  d_in[1];
  const int*   bond_mask = (const int*)  d_in[2];
  const int*   atom_type = (const int*)  d_in[3];
  const float* atom_emb  = (const float*)d_in[4];
  const float* bond_emb  = (const float*)d_in[5];
  const float* w_init    = (const float*)d_in[6];
  const float* mlp_w1    = (const float*)d_in[7];
  const float* mlp_b1    = (const float*)d_in[8];
  const float* mlp_w2    = (const float*)d_in[9];
  const float* lin_s     = (const float*)d_in[10];
  const float* lin_v     = (const float*)d_in[11];
  const float* gate_w    = (const float*)d_in[12];
  const float* hs1       = (const float*)d_in[13];
  const float* hg        = (const float*)d_in[14];
  const float* hs2       = (const float*)d_in[15];
  const float* hv2       = (const float*)d_in[16];
  float* out = (float*)d_out;

  char* ws = (char*)d_ws;
  size_t off_b = 0;
  auto alloc = [&](size_t nbytes){ void* p = (void*)(ws + off_b); off_b += ((nbytes + 255)/256)*256; return p; };
  uint4*    rec     = (uint4*)   alloc((size_t)N_EDGES*48);
  uint4*    msg4    = (uint4*)   alloc((size_t)N_EDGES*256);
  float*    sbuf    = (float*)   alloc((size_t)N_NODES*64*4);
  float*    vbuf    = (float*)   alloc((size_t)N_NODES*48*4);
  float*    agg     = (float*)   alloc((size_t)N_NODES*128*4);
  unsigned short* w2hi = (unsigned short*)alloc((size_t)3*176*64*2);
  unsigned short* w2lo = (unsigned short*)alloc((size_t)3*176*64*2);
  int*      deg_src = (int*)     alloc((size_t)N_NODES*4);   // contiguous with deg_dst -> one memset
  int*      deg_dst = (int*)     alloc((size_t)N_NODES*4);
  int*      off_src = (int*)     alloc((size_t)(N_NODES+1)*4);
  int*      off_dst = (int*)     alloc((size_t)(N_NODES+1)*4);
  int*      cur_src = (int*)     alloc((size_t)N_NODES*4);
  int*      cur_dst = (int*)     alloc((size_t)N_NODES*4);
  int*      csr_src = (int*)     alloc((size_t)N_EDGES*4);
  int*      pos_src = (int*)     alloc((size_t)N_EDGES*4);
  int*      gidx    = (int*)     alloc((size_t)N_EDGES*4);

  dim3 blk(256);
  int gE = (N_EDGES + 255)/256;
  int gN = (N_NODES + 255)/256;
  int gG = (N_NODES + 15)/16;

  hipMemsetAsync(vbuf, 0, (size_t)N_NODES*48*sizeof(float), stream);
  hipMemsetAsync(deg_src, 0, (size_t)2*N_NODES*sizeof(int) + 512, stream);

  count2<<<gE, blk, 0, stream>>>(ei, deg_src, deg_dst);
  scan_deg2<<<2, 1024, 0, stream>>>(deg_src, off_src, cur_src, deg_dst, off_dst, cur_dst);
  scatter_src<<<gE, blk, 0, stream>>>(ei, cur_src, csr_src, pos_src);
  scatter_dst<<<gE, blk, 0, stream>>>(ei, pos_src, cur_dst, gidx);

  prep_edges2<<<gE, blk, 0, stream>>>(pos, ei, bond_mask, bond_emb, csr_src, rec);
  prep_weights<<<(3*176*64 + 255)/256, blk, 0, stream>>>(mlp_w2, w2hi, w2lo);
  init_nodes<<<gN, blk, 0, stream>>>(atom_type, atom_emb, w_init, sbuf);

  for (int l=0;l<3;l++){
    edge_fused2<<<NBLK, blk, 0, stream>>>(rec, sbuf, vbuf,
        mlp_w1 + (size_t)l*16*64, mlp_b1 + (size_t)l*64,
        w2hi + (size_t)l*176*64, w2lo + (size_t)l*176*64,
        lin_v + (size_t)l*96*16,
        msg4);
    gather_nodes<<<gG, blk, 0, stream>>>(msg4, off_dst, gidx, agg);
    node_update<<<gN, blk, 0, stream>>>(agg,
        lin_s + (size_t)l*80*64, gate_w + (size_t)l*64*16, sbuf, vbuf);
  }
  head_kernel<<<gN, blk, 0, stream>>>(sbuf, vbuf, hs1, hg, hs2, hv2, out);
}

// Round 18
// 1129.507 us; speedup vs baseline: 1.2917x; 1.0525x over previous
//
#include <hip/hip_runtime.h>
#include <math.h>

#define N_NODES 30000
#define N_EDGES 480000
#define DEGN 0.25f   // 1/sqrt(16)
#define NBLK 1875    // N_EDGES/256
#define TPITCH 52    // odd dword stride -> conflict-free (verified: 1.32M -> 0)

// Phase fence: stops IR motion + backend scheduling across phase boundaries
// (round-9 lesson: unrestricted motion -> live-range blowup -> 2 GB spill).
#define FENCE() do { asm volatile("" ::: "memory"); __builtin_amdgcn_sched_barrier(0); } while(0)

typedef __attribute__((ext_vector_type(8))) short short8;
typedef __attribute__((ext_vector_type(4))) float f32x4;

__device__ __forceinline__ float fsilu(float x){ return x / (1.f + __expf(-x)); }
__device__ __forceinline__ float fsig (float x){ return 1.f / (1.f + __expf(-x)); }

__device__ __forceinline__ unsigned bf16rn(float x){
  unsigned u = __float_as_uint(x);
  return (u + 0x7fffu + ((u>>16)&1u)) >> 16;
}
__device__ __forceinline__ unsigned pack2(float a, float b){
  return bf16rn(a) | (bf16rn(b)<<16);
}
__device__ __forceinline__ float bflo(unsigned u){ return __uint_as_float(u<<16); }
__device__ __forceinline__ float bfhi(unsigned u){ return __uint_as_float(u & 0xffff0000u); }

// ==================== degree counts (src and dst) ====================
__global__ __launch_bounds__(256) void count2(const int* __restrict__ ei,
                                              int* __restrict__ deg_src,
                                              int* __restrict__ deg_dst)
{
  int e = blockIdx.x*256 + threadIdx.x;
  if (e >= N_EDGES) return;
  atomicAdd(deg_src + ei[e], 1);
  atomicAdd(deg_dst + ei[N_EDGES + e], 1);
}

// 2 blocks: block 0 scans src arrays, block 1 scans dst arrays
__global__ __launch_bounds__(1024) void scan_deg2(
    const int* __restrict__ deg_src, int* __restrict__ off_src, int* __restrict__ cur_src,
    const int* __restrict__ deg_dst, int* __restrict__ off_dst, int* __restrict__ cur_dst)
{
  const int* deg = blockIdx.x ? deg_dst : deg_src;
  int* off = blockIdx.x ? off_dst : off_src;
  int* cur = blockIdx.x ? cur_dst : cur_src;
  __shared__ int part[1024];
  int t = threadIdx.x;
  int base = t*30;
  int local[30];
  int s = 0;
  #pragma unroll
  for (int i=0;i<30;i++){
    int idx = base + i;
    int d = (idx < N_NODES) ? deg[idx] : 0;
    local[i] = s; s += d;
  }
  part[t] = s; __syncthreads();
  for (int stp=1; stp<1024; stp<<=1){
    int v = (t >= stp) ? part[t-stp] : 0;
    __syncthreads();
    part[t] += v;
    __syncthreads();
  }
  int prefix = (t==0) ? 0 : part[t-1];
  #pragma unroll
  for (int i=0;i<30;i++){
    int idx = base + i;
    if (idx < N_NODES){ int o = prefix + local[i]; off[idx] = o; cur[idx] = o; }
  }
  if (t == 1023) off[N_NODES] = part[1023];
}

// src-order scatter: csr_src[m]=e, pos_src[e]=m
__global__ __launch_bounds__(256) void scatter_src(const int* __restrict__ ei,
                                                   int* __restrict__ cur,
                                                   int* __restrict__ csr_src,
                                                   int* __restrict__ pos_src)
{
  int e = blockIdx.x*256 + threadIdx.x;
  if (e >= N_EDGES) return;
  int p = atomicAdd(cur + ei[e], 1);
  csr_src[p] = e;
  pos_src[e] = p;
}

// dst-order scatter of src-positions: gidx[k] = pos_src[e]
__global__ __launch_bounds__(256) void scatter_dst(const int* __restrict__ ei,
                                                   const int* __restrict__ pos_src,
                                                   int* __restrict__ cur,
                                                   int* __restrict__ gidx)
{
  int e = blockIdx.x*256 + threadIdx.x;
  if (e >= N_EDGES) return;
  int p = atomicAdd(cur + ei[N_EDGES + e], 1);
  gidx[p] = pos_src[e];
}

// ==================== per-edge record in SRC order ====================
// rec[k] = 48 B: 8 u32 (16 bf16 ea) | y1x,y1y,y1z f32 | src int
__global__ __launch_bounds__(256) void prep_edges2(
    const float* __restrict__ pos, const int* __restrict__ ei,
    const int* __restrict__ bond_mask, const float* __restrict__ bond_emb,
    const int* __restrict__ csr_src, uint4* __restrict__ rec)
{
  int k = blockIdx.x*256 + threadIdx.x;
  if (k >= N_EDGES) return;
  int e = csr_src[k];
  int src = ei[e], dst = ei[N_EDGES + e];
  float ax = pos[src*3+0], ay = pos[src*3+1], az = pos[src*3+2];
  float bx = pos[dst*3+0], by = pos[dst*3+1], bz = pos[dst*3+2];
  float vx = ax-bx, vy = ay-by, vz = az-bz;
  float r = sqrtf(vx*vx + vy*vy + vz*vz);
  float inv = 1.f / fmaxf(r, 1e-9f);
  const float s3 = 1.7320508075688772f;
  float yx = s3*vx*inv, yy = s3*vy*inv, yz = s3*vz*inv;
  int bm = bond_mask[e];
  float eav[16];
  #pragma unroll
  for (int q=0;q<8;q++) eav[q] = bond_emb[bm*8+q];
  const float step = 5.0f/9.0f;
  #pragma unroll
  for (int j=0;j<8;j++){
    float vj = (float)(j+1)*step;
    float d = (r - vj)/step;
    eav[8+j] = __expf(-d*d) * (1.0f/1.12f);
  }
  uint4 r0, r1, r2;
  r0.x = pack2(eav[0],eav[1]);  r0.y = pack2(eav[2],eav[3]);
  r0.z = pack2(eav[4],eav[5]);  r0.w = pack2(eav[6],eav[7]);
  r1.x = pack2(eav[8],eav[9]);  r1.y = pack2(eav[10],eav[11]);
  r1.z = pack2(eav[12],eav[13]);r1.w = pack2(eav[14],eav[15]);
  r2.x = __float_as_uint(yx); r2.y = __float_as_uint(yy);
  r2.z = __float_as_uint(yz); r2.w = (unsigned)src;
  rec[(size_t)k*3+0] = r0;
  rec[(size_t)k*3+1] = r1;
  rec[(size_t)k*3+2] = r2;
}

// ==================== W2 -> bf16 hi/lo, [176][64] ====================
__global__ void prep_weights(const float* __restrict__ w2,
                             unsigned short* __restrict__ w2hi,
                             unsigned short* __restrict__ w2lo)
{
  int i = blockIdx.x*256 + threadIdx.x;
  if (i >= 3*176*64) return;
  int l = i / (176*64); int rem = i - l*(176*64);
  int n = rem / 64, k = rem - n*64;
  float w = w2[(size_t)l*64*176 + (size_t)k*176 + n];
  unsigned hi = bf16rn(w);
  float lo = w - __uint_as_float(hi<<16);
  w2hi[i] = (unsigned short)hi;
  w2lo[i] = (unsigned short)bf16rn(lo);
}

// ==================== init s ====================
__global__ __launch_bounds__(256) void init_nodes(
    const int* __restrict__ atom_type, const float* __restrict__ atom_emb,
    const float* __restrict__ w_init, float* __restrict__ s)
{
  int n = blockIdx.x*256 + threadIdx.x;
  if (n >= N_NODES) return;
  int t = atom_type[n];
  float acc[64];
  #pragma unroll
  for (int o=0;o<64;o++) acc[o]=0.f;
  for (int k=0;k<64;k++){
    float ek = atom_emb[t*64+k];
    #pragma unroll
    for (int o=0;o<64;o++) acc[o] = fmaf(ek, w_init[k*64+o], acc[o]);
  }
  float4* so = (float4*)(s + (size_t)n*64);
  #pragma unroll
  for (int q=0;q<16;q++) so[q] = make_float4(acc[4*q],acc[4*q+1],acc[4*q+2],acc[4*q+3]);
}

// ==================== fused edge kernel (round 17 structure, kept) ====================
__device__ __forceinline__ void mfma_tile(
    const unsigned short* __restrict__ W2hi, const unsigned short* __restrict__ W2lo,
    int colbase, const short8 (&bfr)[4][2], int wv, int l, unsigned char* tb)
{
  const unsigned short* ap = W2hi + (size_t)(colbase+(l&15))*64 + ((l>>4)*8);
  const unsigned short* aq = W2lo + (size_t)(colbase+(l&15))*64 + ((l>>4)*8);
  short8 ah0 = *(const short8*)ap;
  short8 ah1 = *(const short8*)(ap+32);
  short8 al0 = *(const short8*)aq;
  short8 al1 = *(const short8*)(aq+32);
  #pragma unroll
  for (int ntg=0;ntg<4;ntg++){
    f32x4 acc = {0.f,0.f,0.f,0.f};
    acc = __builtin_amdgcn_mfma_f32_16x16x32_bf16(ah0, bfr[ntg][0], acc, 0,0,0);
    acc = __builtin_amdgcn_mfma_f32_16x16x32_bf16(ah1, bfr[ntg][1], acc, 0,0,0);
    acc = __builtin_amdgcn_mfma_f32_16x16x32_bf16(al0, bfr[ntg][0], acc, 0,0,0);
    acc = __builtin_amdgcn_mfma_f32_16x16x32_bf16(al1, bfr[ntg][1], acc, 0,0,0);
    int e = wv*64 + ntg*16 + (l&15);
    uint2 pk; pk.x = pack2(acc[0],acc[1]); pk.y = pack2(acc[2],acc[3]);
    *(uint2*)(tb + (size_t)e*TPITCH + ((l>>4)*8)) = pk;
  }
}

__device__ __forceinline__ void decode_w(const unsigned char* tb, int t, float* w)
{
  const unsigned char* wr = tb + (size_t)t*TPITCH;
  uint4 c0 = *(const uint4*)wr;
  uint4 c1 = *(const uint4*)(wr+16);
  w[0]=bflo(c0.x); w[1]=bfhi(c0.x); w[2]=bflo(c0.y); w[3]=bfhi(c0.y);
  w[4]=bflo(c0.z); w[5]=bfhi(c0.z); w[6]=bflo(c0.w); w[7]=bfhi(c0.w);
  w[8]=bflo(c1.x); w[9]=bfhi(c1.x); w[10]=bflo(c1.y); w[11]=bfhi(c1.y);
  w[12]=bflo(c1.z); w[13]=bfhi(c1.z); w[14]=bflo(c1.w); w[15]=bfhi(c1.w);
}

__device__ __forceinline__ void consume_sv(const float* w, int i0,
    const float* __restrict__ ssrc, const float* __restrict__ linv, float* a_o)
{
  #pragma unroll
  for (int q4=0;q4<4;q4++){
    float4 s4 = *(const float4*)(ssrc + i0 + q4*4);
    float tq[4] = { w[q4*4+0]*s4.x, w[q4*4+1]*s4.y, w[q4*4+2]*s4.z, w[q4*4+3]*s4.w };
    #pragma unroll
    for (int qq=0;qq<4;qq++){
      int i = i0 + q4*4 + qq;
      float tv = tq[qq];
      #pragma unroll
      for (int o=0;o<16;o++) a_o[o] = fmaf(tv, linv[i*16+o], a_o[o]);
    }
  }
}

// direct wss tile: MFMA C-layout consume (elementwise in col), no LDS
__device__ __forceinline__ void direct_wss(
    const unsigned short* __restrict__ W2hi, const unsigned short* __restrict__ W2lo,
    int colbase, const short8 (&bfr)[4][2], int wv, int l, int src,
    const float* __restrict__ s, uint4* __restrict__ msg4, int kb0)
{
  const unsigned short* ap = W2hi + (size_t)(colbase+(l&15))*64 + ((l>>4)*8);
  const unsigned short* aq = W2lo + (size_t)(colbase+(l&15))*64 + ((l>>4)*8);
  short8 ah0 = *(const short8*)ap;
  short8 ah1 = *(const short8*)(ap+32);
  short8 al0 = *(const short8*)aq;
  short8 al1 = *(const short8*)(aq+32);
  int cb = colbase + ((l>>4)<<2);
  #pragma unroll
  for (int ntg=0;ntg<4;ntg++){
    f32x4 acc = {0.f,0.f,0.f,0.f};
    acc = __builtin_amdgcn_mfma_f32_16x16x32_bf16(ah0, bfr[ntg][0], acc, 0,0,0);
    acc = __builtin_amdgcn_mfma_f32_16x16x32_bf16(ah1, bfr[ntg][1], acc, 0,0,0);
    acc = __builtin_amdgcn_mfma_f32_16x16x32_bf16(al0, bfr[ntg][0], acc, 0,0,0);
    acc = __builtin_amdgcn_mfma_f32_16x16x32_bf16(al1, bfr[ntg][1], acc, 0,0,0);
    int j2 = ntg*16 + (l&15);
    int src2 = __shfl(src, j2);
    float4 s4 = *(const float4*)(s + (size_t)src2*64 + cb);
    uint2 o2;
    o2.x = pack2(DEGN*acc[0]*s4.x, DEGN*acc[1]*s4.y);
    o2.y = pack2(DEGN*acc[2]*s4.z, DEGN*acc[3]*s4.w);
    int ke2 = kb0 + wv*64 + j2;
    unsigned* mb = (unsigned*)(msg4 + ((size_t)(ke2>>1))*32 + (cb>>3)*2 + (ke2&1));
    *(uint2*)(mb + ((cb>>2)&1)*2) = o2;
  }
}

__global__ __launch_bounds__(256)
void edge_fused2(
    const uint4* __restrict__ rec,
    const float* __restrict__ s, const float* __restrict__ v,
    const float* __restrict__ W1,      // [16][64] f32
    const float* __restrict__ b1,      // [64] f32
    const unsigned short* __restrict__ W2hi, // [176][64] bf16
    const unsigned short* __restrict__ W2lo, // [176][64] bf16
    const float* __restrict__ linv,    // [96][16] f32
    uint4* __restrict__ msg4)          // pair-interleaved, src-order index
{
  // H: [0,32768). tbA: [32768,46080). tbB: [46080,59392). Disjoint, wave-local rows.
  __shared__ __align__(16) unsigned char lds[59392];
  int t = threadIdx.x;
  int ke = blockIdx.x*256 + t;

  uint4 r0 = rec[(size_t)ke*3+0];
  uint4 r1 = rec[(size_t)ke*3+1];
  uint4 r2 = rec[(size_t)ke*3+2];
  float yx = __uint_as_float(r2.x), yy = __uint_as_float(r2.y), yz = __uint_as_float(r2.z);
  int src = (int)r2.w;

  // ---- phase H: h = silu(ea@W1+b1) -> LDS (swizzled, own row) ----
  {
    float eav[16];
    eav[0]=bflo(r0.x); eav[1]=bfhi(r0.x); eav[2]=bflo(r0.y); eav[3]=bfhi(r0.y);
    eav[4]=bflo(r0.z); eav[5]=bfhi(r0.z); eav[6]=bflo(r0.w); eav[7]=bfhi(r0.w);
    eav[8]=bflo(r1.x); eav[9]=bfhi(r1.x); eav[10]=bflo(r1.y); eav[11]=bfhi(r1.y);
    eav[12]=bflo(r1.z); eav[13]=bfhi(r1.z); eav[14]=bflo(r1.w); eav[15]=bfhi(r1.w);
    float h[64];
    #pragma unroll
    for (int k=0;k<64;k++) h[k] = b1[k];
    #pragma unroll
    for (int j=0;j<16;j++){
      float a = eav[j];
      #pragma unroll
      for (int k=0;k<64;k++) h[k] = fmaf(a, W1[j*64+k], h[k]);
    }
    #pragma unroll
    for (int k=0;k<64;k++) h[k] = fsilu(h[k]);
    #pragma unroll
    for (int q=0;q<8;q++){
      uint4 hp;
      hp.x = pack2(h[8*q+0],h[8*q+1]); hp.y = pack2(h[8*q+2],h[8*q+3]);
      hp.z = pack2(h[8*q+4],h[8*q+5]); hp.w = pack2(h[8*q+6],h[8*q+7]);
      int byte = (t*128 + q*16) ^ ((t&7)<<4);
      *(uint4*)(lds + byte) = hp;
    }
  }
  FENCE();

  // ---- B-fragments (H rows = this wave's own 64 edges) ----
  int wv = t>>6, l = t&63;
  short8 bfr[4][2];
  #pragma unroll
  for (int ntg=0;ntg<4;ntg++){
    int erow = wv*64 + ntg*16 + (l&15);
    #pragma unroll
    for (int kk=0;kk<2;kk++){
      int byte = (erow*128 + kk*64 + ((l>>4)*16)) ^ ((erow&7)<<4);
      bfr[ntg][kk] = *(const short8*)(lds + byte);
    }
  }
  FENCE();

  unsigned char* tbA = lds + 32768;
  unsigned char* tbB = lds + 46080;
  const float* ssrc = s + (size_t)src*64;
  const float4* vsrc4 = (const float4*)(v + (size_t)src*48);
  uint4* mrow = msg4 + ((size_t)(ke>>1))*32 + (ke&1);

  // ---- sv tiles (cols 80..143): build a_o -- PAIRED (2 tiles/region) ----
  float a_o[16];
  #pragma unroll
  for (int o=0;o<16;o++) a_o[o]=0.f;
  #pragma unroll 1
  for (int st=0; st<2; ++st){
    mfma_tile(W2hi, W2lo, 80+st*32,    bfr, wv, l, tbA);
    mfma_tile(W2hi, W2lo, 80+st*32+16, bfr, wv, l, tbB);
    FENCE();
    float wa[16], wb[16];
    decode_w(tbA, t, wa);
    decode_w(tbB, t, wb);
    consume_sv(wa, st*32,    ssrc, linv, a_o);
    consume_sv(wb, st*32+16, ssrc, linv, a_o);
    FENCE();
  }

  // ---- vv (cols 144..159) -> tbA ; cx (cols 160..175) -> tbB ----
  mfma_tile(W2hi, W2lo, 144, bfr, wv, l, tbA);
  mfma_tile(W2hi, W2lo, 160, bfr, wv, l, tbB);
  FENCE();
  {
    float wvv[16], wcx[16];
    decode_w(tbA, t, wvv);
    decode_w(tbB, t, wcx);
    // two o-halves to cap register pressure
    #pragma unroll 1
    for (int hf=0; hf<2; ++hf){
      int ob = hf*8;
      float av[24];
      #pragma unroll
      for (int q=0;q<24;q++) av[q]=0.f;
      #pragma unroll
      for (int j4=0;j4<4;j4++){
        float4 a = vsrc4[j4*3+0];
        float4 b = vsrc4[j4*3+1];
        float4 c = vsrc4[j4*3+2];
        float vx_[4] = {a.x, a.w, b.z, c.y};
        float vy_[4] = {a.y, b.x, b.w, c.z};
        float vz_[4] = {a.z, b.y, c.x, c.w};
        #pragma unroll
        for (int jj=0;jj<4;jj++){
          int j = j4*4+jj;
          float cxv = vy_[jj]*yz - vz_[jj]*yy;
          float cyv = vz_[jj]*yx - vx_[jj]*yz;
          float czv = vx_[jj]*yy - vy_[jj]*yx;
          float w1 = wvv[j], w2 = wcx[j];
          #pragma unroll
          for (int o=0;o<8;o++){
            float t1 = w1*linv[(64+j)*16+ob+o];
            float t2 = w2*linv[(80+j)*16+ob+o];
            av[o*3+0] = fmaf(t1, vx_[jj], fmaf(t2, cxv, av[o*3+0]));
            av[o*3+1] = fmaf(t1, vy_[jj], fmaf(t2, cyv, av[o*3+1]));
            av[o*3+2] = fmaf(t1, vz_[jj], fmaf(t2, czv, av[o*3+2]));
          }
        }
      }
      #pragma unroll
      for (int o=0;o<8;o++){
        av[o*3+0] = fmaf(a_o[ob+o], yx, av[o*3+0]);
        av[o*3+1] = fmaf(a_o[ob+o], yy, av[o*3+1]);
        av[o*3+2] = fmaf(a_o[ob+o], yz, av[o*3+2]);
      }
      #pragma unroll
      for (int b2=0;b2<3;b2++){
        uint4 p;
        p.x = pack2(DEGN*av[8*b2+0], DEGN*av[8*b2+1]);
        p.y = pack2(DEGN*av[8*b2+2], DEGN*av[8*b2+3]);
        p.z = pack2(DEGN*av[8*b2+4], DEGN*av[8*b2+5]);
        p.w = pack2(DEGN*av[8*b2+6], DEGN*av[8*b2+7]);
        mrow[(10+hf*3+b2)*2] = p;
      }
    }
  }
  FENCE();

  // ---- wss tiles (cols 0..63): DIRECT consume -- PAIRED (2 tiles/region) ----
  int kb0 = blockIdx.x*256;
  #pragma unroll 1
  for (int st=0; st<2; ++st){
    direct_wss(W2hi, W2lo, st*32,    bfr, wv, l, src, s, msg4, kb0);
    direct_wss(W2hi, W2lo, st*32+16, bfr, wv, l, src, s, msg4, kb0);
    FENCE();
  }

  // ---- wvs tile (cols 64..79): DIRECT consume. m_s[64+j] = DEGN*W*(v[j].y) ----
  {
    const unsigned short* ap = W2hi + (size_t)(64+(l&15))*64 + ((l>>4)*8);
    const unsigned short* aq = W2lo + (size_t)(64+(l&15))*64 + ((l>>4)*8);
    short8 ah0 = *(const short8*)ap;
    short8 ah1 = *(const short8*)(ap+32);
    short8 al0 = *(const short8*)aq;
    short8 al1 = *(const short8*)(aq+32);
    int jb = (l>>4)<<2;   // v-channel base 0/4/8/12
    #pragma unroll
    for (int ntg=0;ntg<4;ntg++){
      f32x4 acc = {0.f,0.f,0.f,0.f};
      acc = __builtin_amdgcn_mfma_f32_16x16x32_bf16(ah0, bfr[ntg][0], acc, 0,0,0);
      acc = __builtin_amdgcn_mfma_f32_16x16x32_bf16(ah1, bfr[ntg][1], acc, 0,0,0);
      acc = __builtin_amdgcn_mfma_f32_16x16x32_bf16(al0, bfr[ntg][0], acc, 0,0,0);
      acc = __builtin_amdgcn_mfma_f32_16x16x32_bf16(al1, bfr[ntg][1], acc, 0,0,0);
      int j2 = ntg*16 + (l&15);
      int src2 = __shfl(src, j2);
      float eyx = __shfl(yx, j2), eyy = __shfl(yy, j2), eyz = __shfl(yz, j2);
      const float* vp = v + (size_t)src2*48 + jb*3;
      float4 va = *(const float4*)(vp);
      float4 vb = *(const float4*)(vp+4);
      float4 vc = *(const float4*)(vp+8);
      float d0 = va.x*eyx + va.y*eyy + va.z*eyz;
      float d1 = va.w*eyx + vb.x*eyy + vb.y*eyz;
      float d2 = vb.z*eyx + vb.w*eyy + vc.x*eyz;
      float d3 = vc.y*eyx + vc.z*eyy + vc.w*eyz;
      uint2 o2;
      o2.x = pack2(DEGN*acc[0]*d0, DEGN*acc[1]*d1);
      o2.y = pack2(DEGN*acc[2]*d2, DEGN*acc[3]*d3);
      int ke2 = kb0 + wv*64 + j2;
      int i64 = 64 + jb;
      unsigned* mb = (unsigned*)(msg4 + ((size_t)(ke2>>1))*32 + (i64>>3)*2 + (ke2&1));
      *(uint2*)(mb + ((i64>>2)&1)*2) = o2;
    }
  }
}

// ==================== FUSED gather + node update (round 18) ====================
// Phase 1: dst-CSR gather into LDS rows (16 nodes/block, 16 lanes/node).
// Phase 2: cooperative node update -- lane owns 4 of 64 out-columns;
// gate g via 16-lane shfl_xor butterfly; lane j applies sigmoid(g[j]) to
// its v-channel. agg buffer + node_update launch eliminated.
#define RPAD 132   // padded row stride (f32): staggers banks across nodes
__global__ __launch_bounds__(256) void gather_update(
    const uint4* __restrict__ msg4,
    const int* __restrict__ off,
    const int* __restrict__ gidx,
    const float* __restrict__ lin_s, const float* __restrict__ gate_w,
    float* __restrict__ s, float* __restrict__ v)
{
  __shared__ float rows[16*RPAD];
  int tid = threadIdx.x;
  int nl = tid >> 4;
  int l = tid & 15;
  int n = blockIdx.x*16 + nl;   // N_NODES = 30000 = 1875*16, no tail

  // ---- phase 1: gather 8 channels into LDS row ----
  float acc[8];
  #pragma unroll
  for (int q=0;q<8;q++) acc[q]=0.f;
  int k1 = off[n+1];
  for (int k=off[n]; k<k1; k++){
    int m = gidx[k];
    uint4 mm = msg4[((size_t)(m>>1))*32 + l*2 + (m&1)];
    acc[0] += bflo(mm.x); acc[1] += bfhi(mm.x);
    acc[2] += bflo(mm.y); acc[3] += bfhi(mm.y);
    acc[4] += bflo(mm.z); acc[5] += bfhi(mm.z);
    acc[6] += bflo(mm.w); acc[7] += bfhi(mm.w);
  }
  float* row = rows + nl*RPAD;
  *(float4*)(row + l*8)     = make_float4(acc[0],acc[1],acc[2],acc[3]);
  *(float4*)(row + l*8 + 4) = make_float4(acc[4],acc[5],acc[6],acc[7]);
  __syncthreads();

  // ---- phase 2: outs cols l*4..l*4+3 ----
  float o4[4] = {0.f,0.f,0.f,0.f};
  for (int i=0;i<80;i++){
    float a = row[i];                                  // LDS broadcast within node
    float4 w4 = *(const float4*)(lin_s + i*64 + l*4);  // coalesced across lanes
    o4[0] = fmaf(a, w4.x, o4[0]);
    o4[1] = fmaf(a, w4.y, o4[1]);
    o4[2] = fmaf(a, w4.z, o4[2]);
    o4[3] = fmaf(a, w4.w, o4[3]);
  }
  // s += silu(outs)
  {
    float4 sold = *(const float4*)(s + (size_t)n*64 + l*4);
    float4 snew;
    snew.x = sold.x + fsilu(o4[0]);
    snew.y = sold.y + fsilu(o4[1]);
    snew.z = sold.z + fsilu(o4[2]);
    snew.w = sold.w + fsilu(o4[3]);
    *(float4*)(s + (size_t)n*64 + l*4) = snew;
  }
  // gate partials over this lane's 4 o-values, butterfly-reduce over 16 lanes
  float g[16];
  #pragma unroll
  for (int j=0;j<16;j++) g[j]=0.f;
  #pragma unroll
  for (int c=0;c<4;c++){
    float x = o4[c];
    int o = l*4+c;
    #pragma unroll
    for (int j=0;j<16;j++) g[j] = fmaf(x, gate_w[o*16+j], g[j]);
  }
  #pragma unroll
  for (int m2=1; m2<16; m2<<=1){
    #pragma unroll
    for (int j=0;j<16;j++) g[j] += __shfl_xor(g[j], m2);
  }
  // v channel j = l
  float gv = fsig(g[l]);
  float* vp = v + (size_t)n*48 + l*3;
  vp[0] += row[80+l*3+0]*gv;
  vp[1] += row[80+l*3+1]*gv;
  vp[2] += row[80+l*3+2]*gv;
}

// ==================== output head ====================
__global__ __launch_bounds__(256) void head_kernel(
    const float* __restrict__ s, const float* __restrict__ v,
    const float* __restrict__ hs1, const float* __restrict__ hg,
    const float* __restrict__ hs2, const float* __restrict__ hv2,
    float* __restrict__ out)
{
  int n = blockIdx.x*256 + threadIdx.x;
  if (n >= N_NODES) return;
  float sv[64];
  const float4* sp = (const float4*)(s + (size_t)n*64);
  #pragma unroll
  for (int q=0;q<16;q++){ float4 t=sp[q]; sv[4*q]=t.x; sv[4*q+1]=t.y; sv[4*q+2]=t.z; sv[4*q+3]=t.w; }
  float h[64];
  #pragma unroll
  for (int o=0;o<64;o++) h[o]=0.f;
  for (int k=0;k<64;k++){
    float x = sv[k];
    #pragma unroll
    for (int o=0;o<64;o++) h[o] = fmaf(x, hs1[k*64+o], h[o]);
  }
  #pragma unroll
  for (int o=0;o<64;o++) h[o] = fsilu(h[o]);
  float g[16];
  #pragma unroll
  for (int j=0;j<16;j++) g[j]=0.f;
  float ps = 0.f;
  for (int o=0;o<64;o++){
    float x = h[o];
    #pragma unroll
    for (int j=0;j<16;j++) g[j] = fmaf(x, hg[o*16+j], g[j]);
    ps = fmaf(x, hs2[o], ps);
  }
  float pvx=0.f, pvy=0.f, pvz=0.f;
  #pragma unroll
  for (int j=0;j<16;j++){
    float gv = fsig(g[j]) * hv2[j];
    pvx = fmaf(v[(size_t)n*48+j*3+0], gv, pvx);
    pvy = fmaf(v[(size_t)n*48+j*3+1], gv, pvy);
    pvz = fmaf(v[(size_t)n*48+j*3+2], gv, pvz);
  }
  *(float4*)(out + (size_t)n*4) = make_float4(ps, pvx, pvy, pvz);
}

extern "C" void kernel_launch(void* const* d_in, const int* in_sizes, int n_in,
                              void* d_out, int out_size, void* d_ws, size_t ws_size,
                              hipStream_t stream)
{
  const float* pos       = (const float*)d_in[0];
  const int*   ei        = (const int*)  d_in[1];
  const int*   bond_mask = (const int*)  d_in[2];
  const int*   atom_type = (const int*)  d_in[3];
  const float* atom_emb  = (const float*)d_in[4];
  const float* bond_emb  = (const float*)d_in[5];
  const float* w_init    = (const float*)d_in[6];
  const float* mlp_w1    = (const float*)d_in[7];
  const float* mlp_b1    = (const float*)d_in[8];
  const float* mlp_w2    = (const float*)d_in[9];
  const float* lin_s     = (const float*)d_in[10];
  const float* lin_v     = (const float*)d_in[11];
  const float* gate_w    = (const float*)d_in[12];
  const float* hs1       = (const float*)d_in[13];
  const float* hg        = (const float*)d_in[14];
  const float* hs2       = (const float*)d_in[15];
  const float* hv2       = (const float*)d_in[16];
  float* out = (float*)d_out;

  char* ws = (char*)d_ws;
  size_t off_b = 0;
  auto alloc = [&](size_t nbytes){ void* p = (void*)(ws + off_b); off_b += ((nbytes + 255)/256)*256; return p; };
  uint4*    rec     = (uint4*)   alloc((size_t)N_EDGES*48);
  uint4*    msg4    = (uint4*)   alloc((size_t)N_EDGES*256);
  float*    sbuf    = (float*)   alloc((size_t)N_NODES*64*4);
  float*    vbuf    = (float*)   alloc((size_t)N_NODES*48*4);
  unsigned short* w2hi = (unsigned short*)alloc((size_t)3*176*64*2);
  unsigned short* w2lo = (unsigned short*)alloc((size_t)3*176*64*2);
  int*      deg_src = (int*)     alloc((size_t)N_NODES*4);   // contiguous with deg_dst -> one memset
  int*      deg_dst = (int*)     alloc((size_t)N_NODES*4);
  int*      off_src = (int*)     alloc((size_t)(N_NODES+1)*4);
  int*      off_dst = (int*)     alloc((size_t)(N_NODES+1)*4);
  int*      cur_src = (int*)     alloc((size_t)N_NODES*4);
  int*      cur_dst = (int*)     alloc((size_t)N_NODES*4);
  int*      csr_src = (int*)     alloc((size_t)N_EDGES*4);
  int*      pos_src = (int*)     alloc((size_t)N_EDGES*4);
  int*      gidx    = (int*)     alloc((size_t)N_EDGES*4);

  dim3 blk(256);
  int gE = (N_EDGES + 255)/256;
  int gN = (N_NODES + 255)/256;
  int gG = (N_NODES + 15)/16;

  hipMemsetAsync(vbuf, 0, (size_t)N_NODES*48*sizeof(float), stream);
  hipMemsetAsync(deg_src, 0, (size_t)2*N_NODES*sizeof(int) + 512, stream);

  count2<<<gE, blk, 0, stream>>>(ei, deg_src, deg_dst);
  scan_deg2<<<2, 1024, 0, stream>>>(deg_src, off_src, cur_src, deg_dst, off_dst, cur_dst);
  scatter_src<<<gE, blk, 0, stream>>>(ei, cur_src, csr_src, pos_src);
  scatter_dst<<<gE, blk, 0, stream>>>(ei, pos_src, cur_dst, gidx);

  prep_edges2<<<gE, blk, 0, stream>>>(pos, ei, bond_mask, bond_emb, csr_src, rec);
  prep_weights<<<(3*176*64 + 255)/256, blk, 0, stream>>>(mlp_w2, w2hi, w2lo);
  init_nodes<<<gN, blk, 0, stream>>>(atom_type, atom_emb, w_init, sbuf);

  for (int l=0;l<3;l++){
    edge_fused2<<<NBLK, blk, 0, stream>>>(rec, sbuf, vbuf,
        mlp_w1 + (size_t)l*16*64, mlp_b1 + (size_t)l*64,
        w2hi + (size_t)l*176*64, w2lo + (size_t)l*176*64,
        lin_v + (size_t)l*96*16,
        msg4);
    gather_update<<<gG, blk, 0, stream>>>(msg4, off_dst, gidx,
        lin_s + (size_t)l*80*64, gate_w + (size_t)l*64*16, sbuf, vbuf);
  }
  head_kernel<<<gN, blk, 0, stream>>>(sbuf, vbuf, hs1, hg, hs2, hv2, out);
}

// Round 19
// 1064.584 us; speedup vs baseline: 1.3705x; 1.0610x over previous
//
#include <hip/hip_runtime.h>
#include <math.h>

#define N_NODES 30000
#define N_EDGES 480000
#define DEGN 0.25f   // 1/sqrt(16)
#define NBLK 1875    // N_EDGES/256
#define TPITCH 52    // odd dword stride -> conflict-free (verified: 1.32M -> 0)

// Phase fence: stops IR motion + backend scheduling across phase boundaries
// (round-9 lesson: unrestricted motion -> live-range blowup -> 2 GB spill).
#define FENCE() do { asm volatile("" ::: "memory"); __builtin_amdgcn_sched_barrier(0); } while(0)

typedef __attribute__((ext_vector_type(8))) short short8;
typedef __attribute__((ext_vector_type(4))) float f32x4;

__device__ __forceinline__ float fsilu(float x){ return x / (1.f + __expf(-x)); }
__device__ __forceinline__ float fsig (float x){ return 1.f / (1.f + __expf(-x)); }

__device__ __forceinline__ unsigned bf16rn(float x){
  unsigned u = __float_as_uint(x);
  return (u + 0x7fffu + ((u>>16)&1u)) >> 16;
}
__device__ __forceinline__ unsigned pack2(float a, float b){
  return bf16rn(a) | (bf16rn(b)<<16);
}
__device__ __forceinline__ float bflo(unsigned u){ return __uint_as_float(u<<16); }
__device__ __forceinline__ float bfhi(unsigned u){ return __uint_as_float(u & 0xffff0000u); }

// ==================== degree counts (src and dst) ====================
__global__ __launch_bounds__(256) void count2(const int* __restrict__ ei,
                                              int* __restrict__ deg_src,
                                              int* __restrict__ deg_dst)
{
  int e = blockIdx.x*256 + threadIdx.x;
  if (e >= N_EDGES) return;
  atomicAdd(deg_src + ei[e], 1);
  atomicAdd(deg_dst + ei[N_EDGES + e], 1);
}

// 2 blocks: block 0 scans src arrays, block 1 scans dst arrays
__global__ __launch_bounds__(1024) void scan_deg2(
    const int* __restrict__ deg_src, int* __restrict__ off_src, int* __restrict__ cur_src,
    const int* __restrict__ deg_dst, int* __restrict__ off_dst, int* __restrict__ cur_dst)
{
  const int* deg = blockIdx.x ? deg_dst : deg_src;
  int* off = blockIdx.x ? off_dst : off_src;
  int* cur = blockIdx.x ? cur_dst : cur_src;
  __shared__ int part[1024];
  int t = threadIdx.x;
  int base = t*30;
  int local[30];
  int s = 0;
  #pragma unroll
  for (int i=0;i<30;i++){
    int idx = base + i;
    int d = (idx < N_NODES) ? deg[idx] : 0;
    local[i] = s; s += d;
  }
  part[t] = s; __syncthreads();
  for (int stp=1; stp<1024; stp<<=1){
    int v = (t >= stp) ? part[t-stp] : 0;
    __syncthreads();
    part[t] += v;
    __syncthreads();
  }
  int prefix = (t==0) ? 0 : part[t-1];
  #pragma unroll
  for (int i=0;i<30;i++){
    int idx = base + i;
    if (idx < N_NODES){ int o = prefix + local[i]; off[idx] = o; cur[idx] = o; }
  }
  if (t == 1023) off[N_NODES] = part[1023];
}

// src-order scatter: csr_src[m]=e, pos_src[e]=m
__global__ __launch_bounds__(256) void scatter_src(const int* __restrict__ ei,
                                                   int* __restrict__ cur,
                                                   int* __restrict__ csr_src,
                                                   int* __restrict__ pos_src)
{
  int e = blockIdx.x*256 + threadIdx.x;
  if (e >= N_EDGES) return;
  int p = atomicAdd(cur + ei[e], 1);
  csr_src[p] = e;
  pos_src[e] = p;
}

// dst-order scatter of src-positions: gidx[k] = pos_src[e]
__global__ __launch_bounds__(256) void scatter_dst(const int* __restrict__ ei,
                                                   const int* __restrict__ pos_src,
                                                   int* __restrict__ cur,
                                                   int* __restrict__ gidx)
{
  int e = blockIdx.x*256 + threadIdx.x;
  if (e >= N_EDGES) return;
  int p = atomicAdd(cur + ei[N_EDGES + e], 1);
  gidx[p] = pos_src[e];
}

// ==================== per-edge record in SRC order ====================
// rec[k] = 48 B: 8 u32 (16 bf16 ea) | y1x,y1y,y1z f32 | src int
__global__ __launch_bounds__(256) void prep_edges2(
    const float* __restrict__ pos, const int* __restrict__ ei,
    const int* __restrict__ bond_mask, const float* __restrict__ bond_emb,
    const int* __restrict__ csr_src, uint4* __restrict__ rec)
{
  int k = blockIdx.x*256 + threadIdx.x;
  if (k >= N_EDGES) return;
  int e = csr_src[k];
  int src = ei[e], dst = ei[N_EDGES + e];
  float ax = pos[src*3+0], ay = pos[src*3+1], az = pos[src*3+2];
  float bx = pos[dst*3+0], by = pos[dst*3+1], bz = pos[dst*3+2];
  float vx = ax-bx, vy = ay-by, vz = az-bz;
  float r = sqrtf(vx*vx + vy*vy + vz*vz);
  float inv = 1.f / fmaxf(r, 1e-9f);
  const float s3 = 1.7320508075688772f;
  float yx = s3*vx*inv, yy = s3*vy*inv, yz = s3*vz*inv;
  int bm = bond_mask[e];
  float eav[16];
  #pragma unroll
  for (int q=0;q<8;q++) eav[q] = bond_emb[bm*8+q];
  const float step = 5.0f/9.0f;
  #pragma unroll
  for (int j=0;j<8;j++){
    float vj = (float)(j+1)*step;
    float d = (r - vj)/step;
    eav[8+j] = __expf(-d*d) * (1.0f/1.12f);
  }
  uint4 r0, r1, r2;
  r0.x = pack2(eav[0],eav[1]);  r0.y = pack2(eav[2],eav[3]);
  r0.z = pack2(eav[4],eav[5]);  r0.w = pack2(eav[6],eav[7]);
  r1.x = pack2(eav[8],eav[9]);  r1.y = pack2(eav[10],eav[11]);
  r1.z = pack2(eav[12],eav[13]);r1.w = pack2(eav[14],eav[15]);
  r2.x = __float_as_uint(yx); r2.y = __float_as_uint(yy);
  r2.z = __float_as_uint(yz); r2.w = (unsigned)src;
  rec[(size_t)k*3+0] = r0;
  rec[(size_t)k*3+1] = r1;
  rec[(size_t)k*3+2] = r2;
}

// ==================== W2 -> bf16 (single precision), [176][64] ====================
__global__ void prep_weights(const float* __restrict__ w2,
                             unsigned short* __restrict__ w2hi)
{
  int i = blockIdx.x*256 + threadIdx.x;
  if (i >= 3*176*64) return;
  int l = i / (176*64); int rem = i - l*(176*64);
  int n = rem / 64, k = rem - n*64;
  float w = w2[(size_t)l*64*176 + (size_t)k*176 + n];
  w2hi[i] = (unsigned short)bf16rn(w);
}

// ==================== init s ====================
__global__ __launch_bounds__(256) void init_nodes(
    const int* __restrict__ atom_type, const float* __restrict__ atom_emb,
    const float* __restrict__ w_init, float* __restrict__ s)
{
  int n = blockIdx.x*256 + threadIdx.x;
  if (n >= N_NODES) return;
  int t = atom_type[n];
  float acc[64];
  #pragma unroll
  for (int o=0;o<64;o++) acc[o]=0.f;
  for (int k=0;k<64;k++){
    float ek = atom_emb[t*64+k];
    #pragma unroll
    for (int o=0;o<64;o++) acc[o] = fmaf(ek, w_init[k*64+o], acc[o]);
  }
  float4* so = (float4*)(s + (size_t)n*64);
  #pragma unroll
  for (int q=0;q<16;q++) so[q] = make_float4(acc[4*q],acc[4*q+1],acc[4*q+2],acc[4*q+3]);
}

// ==================== fused edge kernel (round 19: single-MFMA W2) ====================
// Round-18 structure; hi/lo error-correction MFMA dropped (W2 single bf16).
// Halves MFMA issue + W2 A-load per region; absmax budget 0.03 < 0.0566.
__device__ __forceinline__ void mfma_tile(
    const unsigned short* __restrict__ W2hi,
    int colbase, const short8 (&bfr)[4][2], int wv, int l, unsigned char* tb)
{
  const unsigned short* ap = W2hi + (size_t)(colbase+(l&15))*64 + ((l>>4)*8);
  short8 ah0 = *(const short8*)ap;
  short8 ah1 = *(const short8*)(ap+32);
  #pragma unroll
  for (int ntg=0;ntg<4;ntg++){
    f32x4 acc = {0.f,0.f,0.f,0.f};
    acc = __builtin_amdgcn_mfma_f32_16x16x32_bf16(ah0, bfr[ntg][0], acc, 0,0,0);
    acc = __builtin_amdgcn_mfma_f32_16x16x32_bf16(ah1, bfr[ntg][1], acc, 0,0,0);
    int e = wv*64 + ntg*16 + (l&15);
    uint2 pk; pk.x = pack2(acc[0],acc[1]); pk.y = pack2(acc[2],acc[3]);
    *(uint2*)(tb + (size_t)e*TPITCH + ((l>>4)*8)) = pk;
  }
}

__device__ __forceinline__ void decode_w(const unsigned char* tb, int t, float* w)
{
  const unsigned char* wr = tb + (size_t)t*TPITCH;
  uint4 c0 = *(const uint4*)wr;
  uint4 c1 = *(const uint4*)(wr+16);
  w[0]=bflo(c0.x); w[1]=bfhi(c0.x); w[2]=bflo(c0.y); w[3]=bfhi(c0.y);
  w[4]=bflo(c0.z); w[5]=bfhi(c0.z); w[6]=bflo(c0.w); w[7]=bfhi(c0.w);
  w[8]=bflo(c1.x); w[9]=bfhi(c1.x); w[10]=bflo(c1.y); w[11]=bfhi(c1.y);
  w[12]=bflo(c1.z); w[13]=bfhi(c1.z); w[14]=bflo(c1.w); w[15]=bfhi(c1.w);
}

__device__ __forceinline__ void consume_sv(const float* w, int i0,
    const float* __restrict__ ssrc, const float* __restrict__ linv, float* a_o)
{
  #pragma unroll
  for (int q4=0;q4<4;q4++){
    float4 s4 = *(const float4*)(ssrc + i0 + q4*4);
    float tq[4] = { w[q4*4+0]*s4.x, w[q4*4+1]*s4.y, w[q4*4+2]*s4.z, w[q4*4+3]*s4.w };
    #pragma unroll
    for (int qq=0;qq<4;qq++){
      int i = i0 + q4*4 + qq;
      float tv = tq[qq];
      #pragma unroll
      for (int o=0;o<16;o++) a_o[o] = fmaf(tv, linv[i*16+o], a_o[o]);
    }
  }
}

// direct wss tile: MFMA C-layout consume (elementwise in col), no LDS
__device__ __forceinline__ void direct_wss(
    const unsigned short* __restrict__ W2hi,
    int colbase, const short8 (&bfr)[4][2], int wv, int l, int src,
    const float* __restrict__ s, uint4* __restrict__ msg4, int kb0)
{
  const unsigned short* ap = W2hi + (size_t)(colbase+(l&15))*64 + ((l>>4)*8);
  short8 ah0 = *(const short8*)ap;
  short8 ah1 = *(const short8*)(ap+32);
  int cb = colbase + ((l>>4)<<2);
  #pragma unroll
  for (int ntg=0;ntg<4;ntg++){
    f32x4 acc = {0.f,0.f,0.f,0.f};
    acc = __builtin_amdgcn_mfma_f32_16x16x32_bf16(ah0, bfr[ntg][0], acc, 0,0,0);
    acc = __builtin_amdgcn_mfma_f32_16x16x32_bf16(ah1, bfr[ntg][1], acc, 0,0,0);
    int j2 = ntg*16 + (l&15);
    int src2 = __shfl(src, j2);
    float4 s4 = *(const float4*)(s + (size_t)src2*64 + cb);
    uint2 o2;
    o2.x = pack2(DEGN*acc[0]*s4.x, DEGN*acc[1]*s4.y);
    o2.y = pack2(DEGN*acc[2]*s4.z, DEGN*acc[3]*s4.w);
    int ke2 = kb0 + wv*64 + j2;
    unsigned* mb = (unsigned*)(msg4 + ((size_t)(ke2>>1))*32 + (cb>>3)*2 + (ke2&1));
    *(uint2*)(mb + ((cb>>2)&1)*2) = o2;
  }
}

__global__ __launch_bounds__(256)
void edge_fused2(
    const uint4* __restrict__ rec,
    const float* __restrict__ s, const float* __restrict__ v,
    const float* __restrict__ W1,      // [16][64] f32
    const float* __restrict__ b1,      // [64] f32
    const unsigned short* __restrict__ W2hi, // [176][64] bf16
    const float* __restrict__ linv,    // [96][16] f32
    uint4* __restrict__ msg4)          // pair-interleaved, src-order index
{
  // H: [0,32768). tbA: [32768,46080). tbB: [46080,59392). Disjoint, wave-local rows.
  __shared__ __align__(16) unsigned char lds[59392];
  int t = threadIdx.x;
  int ke = blockIdx.x*256 + t;

  uint4 r0 = rec[(size_t)ke*3+0];
  uint4 r1 = rec[(size_t)ke*3+1];
  uint4 r2 = rec[(size_t)ke*3+2];
  float yx = __uint_as_float(r2.x), yy = __uint_as_float(r2.y), yz = __uint_as_float(r2.z);
  int src = (int)r2.w;

  // ---- phase H: h = silu(ea@W1+b1) -> LDS (swizzled, own row) ----
  {
    float eav[16];
    eav[0]=bflo(r0.x); eav[1]=bfhi(r0.x); eav[2]=bflo(r0.y); eav[3]=bfhi(r0.y);
    eav[4]=bflo(r0.z); eav[5]=bfhi(r0.z); eav[6]=bflo(r0.w); eav[7]=bfhi(r0.w);
    eav[8]=bflo(r1.x); eav[9]=bfhi(r1.x); eav[10]=bflo(r1.y); eav[11]=bfhi(r1.y);
    eav[12]=bflo(r1.z); eav[13]=bfhi(r1.z); eav[14]=bflo(r1.w); eav[15]=bfhi(r1.w);
    float h[64];
    #pragma unroll
    for (int k=0;k<64;k++) h[k] = b1[k];
    #pragma unroll
    for (int j=0;j<16;j++){
      float a = eav[j];
      #pragma unroll
      for (int k=0;k<64;k++) h[k] = fmaf(a, W1[j*64+k], h[k]);
    }
    #pragma unroll
    for (int k=0;k<64;k++) h[k] = fsilu(h[k]);
    #pragma unroll
    for (int q=0;q<8;q++){
      uint4 hp;
      hp.x = pack2(h[8*q+0],h[8*q+1]); hp.y = pack2(h[8*q+2],h[8*q+3]);
      hp.z = pack2(h[8*q+4],h[8*q+5]); hp.w = pack2(h[8*q+6],h[8*q+7]);
      int byte = (t*128 + q*16) ^ ((t&7)<<4);
      *(uint4*)(lds + byte) = hp;
    }
  }
  FENCE();

  // ---- B-fragments (H rows = this wave's own 64 edges) ----
  int wv = t>>6, l = t&63;
  short8 bfr[4][2];
  #pragma unroll
  for (int ntg=0;ntg<4;ntg++){
    int erow = wv*64 + ntg*16 + (l&15);
    #pragma unroll
    for (int kk=0;kk<2;kk++){
      int byte = (erow*128 + kk*64 + ((l>>4)*16)) ^ ((erow&7)<<4);
      bfr[ntg][kk] = *(const short8*)(lds + byte);
    }
  }
  FENCE();

  unsigned char* tbA = lds + 32768;
  unsigned char* tbB = lds + 46080;
  const float* ssrc = s + (size_t)src*64;
  const float4* vsrc4 = (const float4*)(v + (size_t)src*48);
  uint4* mrow = msg4 + ((size_t)(ke>>1))*32 + (ke&1);

  // ---- sv tiles (cols 80..143): build a_o -- PAIRED (2 tiles/region) ----
  float a_o[16];
  #pragma unroll
  for (int o=0;o<16;o++) a_o[o]=0.f;
  #pragma unroll 1
  for (int st=0; st<2; ++st){
    mfma_tile(W2hi, 80+st*32,    bfr, wv, l, tbA);
    mfma_tile(W2hi, 80+st*32+16, bfr, wv, l, tbB);
    FENCE();
    float wa[16], wb[16];
    decode_w(tbA, t, wa);
    decode_w(tbB, t, wb);
    consume_sv(wa, st*32,    ssrc, linv, a_o);
    consume_sv(wb, st*32+16, ssrc, linv, a_o);
    FENCE();
  }

  // ---- vv (cols 144..159) -> tbA ; cx (cols 160..175) -> tbB ----
  mfma_tile(W2hi, 144, bfr, wv, l, tbA);
  mfma_tile(W2hi, 160, bfr, wv, l, tbB);
  FENCE();
  {
    float wvv[16], wcx[16];
    decode_w(tbA, t, wvv);
    decode_w(tbB, t, wcx);
    // two o-halves to cap register pressure
    #pragma unroll 1
    for (int hf=0; hf<2; ++hf){
      int ob = hf*8;
      float av[24];
      #pragma unroll
      for (int q=0;q<24;q++) av[q]=0.f;
      #pragma unroll
      for (int j4=0;j4<4;j4++){
        float4 a = vsrc4[j4*3+0];
        float4 b = vsrc4[j4*3+1];
        float4 c = vsrc4[j4*3+2];
        float vx_[4] = {a.x, a.w, b.z, c.y};
        float vy_[4] = {a.y, b.x, b.w, c.z};
        float vz_[4] = {a.z, b.y, c.x, c.w};
        #pragma unroll
        for (int jj=0;jj<4;jj++){
          int j = j4*4+jj;
          float cxv = vy_[jj]*yz - vz_[jj]*yy;
          float cyv = vz_[jj]*yx - vx_[jj]*yz;
          float czv = vx_[jj]*yy - vy_[jj]*yx;
          float w1 = wvv[j], w2 = wcx[j];
          #pragma unroll
          for (int o=0;o<8;o++){
            float t1 = w1*linv[(64+j)*16+ob+o];
            float t2 = w2*linv[(80+j)*16+ob+o];
            av[o*3+0] = fmaf(t1, vx_[jj], fmaf(t2, cxv, av[o*3+0]));
            av[o*3+1] = fmaf(t1, vy_[jj], fmaf(t2, cyv, av[o*3+1]));
            av[o*3+2] = fmaf(t1, vz_[jj], fmaf(t2, czv, av[o*3+2]));
          }
        }
      }
      #pragma unroll
      for (int o=0;o<8;o++){
        av[o*3+0] = fmaf(a_o[ob+o], yx, av[o*3+0]);
        av[o*3+1] = fmaf(a_o[ob+o], yy, av[o*3+1]);
        av[o*3+2] = fmaf(a_o[ob+o], yz, av[o*3+2]);
      }
      #pragma unroll
      for (int b2=0;b2<3;b2++){
        uint4 p;
        p.x = pack2(DEGN*av[8*b2+0], DEGN*av[8*b2+1]);
        p.y = pack2(DEGN*av[8*b2+2], DEGN*av[8*b2+3]);
        p.z = pack2(DEGN*av[8*b2+4], DEGN*av[8*b2+5]);
        p.w = pack2(DEGN*av[8*b2+6], DEGN*av[8*b2+7]);
        mrow[(10+hf*3+b2)*2] = p;
      }
    }
  }
  FENCE();

  // ---- wss tiles (cols 0..63): DIRECT consume -- PAIRED (2 tiles/region) ----
  int kb0 = blockIdx.x*256;
  #pragma unroll 1
  for (int st=0; st<2; ++st){
    direct_wss(W2hi, st*32,    bfr, wv, l, src, s, msg4, kb0);
    direct_wss(W2hi, st*32+16, bfr, wv, l, src, s, msg4, kb0);
    FENCE();
  }

  // ---- wvs tile (cols 64..79): DIRECT consume. m_s[64+j] = DEGN*W*(v[j].y) ----
  {
    const unsigned short* ap = W2hi + (size_t)(64+(l&15))*64 + ((l>>4)*8);
    short8 ah0 = *(const short8*)ap;
    short8 ah1 = *(const short8*)(ap+32);
    int jb = (l>>4)<<2;   // v-channel base 0/4/8/12
    #pragma unroll
    for (int ntg=0;ntg<4;ntg++){
      f32x4 acc = {0.f,0.f,0.f,0.f};
      acc = __builtin_amdgcn_mfma_f32_16x16x32_bf16(ah0, bfr[ntg][0], acc, 0,0,0);
      acc = __builtin_amdgcn_mfma_f32_16x16x32_bf16(ah1, bfr[ntg][1], acc, 0,0,0);
      int j2 = ntg*16 + (l&15);
      int src2 = __shfl(src, j2);
      float eyx = __shfl(yx, j2), eyy = __shfl(yy, j2), eyz = __shfl(yz, j2);
      const float* vp = v + (size_t)src2*48 + jb*3;
      float4 va = *(const float4*)(vp);
      float4 vb = *(const float4*)(vp+4);
      float4 vc = *(const float4*)(vp+8);
      float d0 = va.x*eyx + va.y*eyy + va.z*eyz;
      float d1 = va.w*eyx + vb.x*eyy + vb.y*eyz;
      float d2 = vb.z*eyx + vb.w*eyy + vc.x*eyz;
      float d3 = vc.y*eyx + vc.z*eyy + vc.w*eyz;
      uint2 o2;
      o2.x = pack2(DEGN*acc[0]*d0, DEGN*acc[1]*d1);
      o2.y = pack2(DEGN*acc[2]*d2, DEGN*acc[3]*d3);
      int ke2 = kb0 + wv*64 + j2;
      int i64 = 64 + jb;
      unsigned* mb = (unsigned*)(msg4 + ((size_t)(ke2>>1))*32 + (i64>>3)*2 + (ke2&1));
      *(uint2*)(mb + ((i64>>2)&1)*2) = o2;
    }
  }
}

// ==================== FUSED gather + node update ====================
#define RPAD 132   // padded row stride (f32): staggers banks across nodes
__global__ __launch_bounds__(256) void gather_update(
    const uint4* __restrict__ msg4,
    const int* __restrict__ off,
    const int* __restrict__ gidx,
    const float* __restrict__ lin_s, const float* __restrict__ gate_w,
    float* __restrict__ s, float* __restrict__ v)
{
  __shared__ float rows[16*RPAD];
  int tid = threadIdx.x;
  int nl = tid >> 4;
  int l = tid & 15;
  int n = blockIdx.x*16 + nl;   // N_NODES = 30000 = 1875*16, no tail

  // ---- phase 1: gather 8 channels into LDS row ----
  float acc[8];
  #pragma unroll
  for (int q=0;q<8;q++) acc[q]=0.f;
  int k1 = off[n+1];
  for (int k=off[n]; k<k1; k++){
    int m = gidx[k];
    uint4 mm = msg4[((size_t)(m>>1))*32 + l*2 + (m&1)];
    acc[0] += bflo(mm.x); acc[1] += bfhi(mm.x);
    acc[2] += bflo(mm.y); acc[3] += bfhi(mm.y);
    acc[4] += bflo(mm.z); acc[5] += bfhi(mm.z);
    acc[6] += bflo(mm.w); acc[7] += bfhi(mm.w);
  }
  float* row = rows + nl*RPAD;
  *(float4*)(row + l*8)     = make_float4(acc[0],acc[1],acc[2],acc[3]);
  *(float4*)(row + l*8 + 4) = make_float4(acc[4],acc[5],acc[6],acc[7]);
  __syncthreads();

  // ---- phase 2: outs cols l*4..l*4+3 ----
  float o4[4] = {0.f,0.f,0.f,0.f};
  for (int i=0;i<80;i++){
    float a = row[i];                                  // LDS broadcast within node
    float4 w4 = *(const float4*)(lin_s + i*64 + l*4);  // coalesced across lanes
    o4[0] = fmaf(a, w4.x, o4[0]);
    o4[1] = fmaf(a, w4.y, o4[1]);
    o4[2] = fmaf(a, w4.z, o4[2]);
    o4[3] = fmaf(a, w4.w, o4[3]);
  }
  // s += silu(outs)
  {
    float4 sold = *(const float4*)(s + (size_t)n*64 + l*4);
    float4 snew;
    snew.x = sold.x + fsilu(o4[0]);
    snew.y = sold.y + fsilu(o4[1]);
    snew.z = sold.z + fsilu(o4[2]);
    snew.w = sold.w + fsilu(o4[3]);
    *(float4*)(s + (size_t)n*64 + l*4) = snew;
  }
  // gate partials over this lane's 4 o-values, butterfly-reduce over 16 lanes
  float g[16];
  #pragma unroll
  for (int j=0;j<16;j++) g[j]=0.f;
  #pragma unroll
  for (int c=0;c<4;c++){
    float x = o4[c];
    int o = l*4+c;
    #pragma unroll
    for (int j=0;j<16;j++) g[j] = fmaf(x, gate_w[o*16+j], g[j]);
  }
  #pragma unroll
  for (int m2=1; m2<16; m2<<=1){
    #pragma unroll
    for (int j=0;j<16;j++) g[j] += __shfl_xor(g[j], m2);
  }
  // v channel j = l
  float gv = fsig(g[l]);
  float* vp = v + (size_t)n*48 + l*3;
  vp[0] += row[80+l*3+0]*gv;
  vp[1] += row[80+l*3+1]*gv;
  vp[2] += row[80+l*3+2]*gv;
}

// ==================== output head ====================
__global__ __launch_bounds__(256) void head_kernel(
    const float* __restrict__ s, const float* __restrict__ v,
    const float* __restrict__ hs1, const float* __restrict__ hg,
    const float* __restrict__ hs2, const float* __restrict__ hv2,
    float* __restrict__ out)
{
  int n = blockIdx.x*256 + threadIdx.x;
  if (n >= N_NODES) return;
  float sv[64];
  const float4* sp = (const float4*)(s + (size_t)n*64);
  #pragma unroll
  for (int q=0;q<16;q++){ float4 t=sp[q]; sv[4*q]=t.x; sv[4*q+1]=t.y; sv[4*q+2]=t.z; sv[4*q+3]=t.w; }
  float h[64];
  #pragma unroll
  for (int o=0;o<64;o++) h[o]=0.f;
  for (int k=0;k<64;k++){
    float x = sv[k];
    #pragma unroll
    for (int o=0;o<64;o++) h[o] = fmaf(x, hs1[k*64+o], h[o]);
  }
  #pragma unroll
  for (int o=0;o<64;o++) h[o] = fsilu(h[o]);
  float g[16];
  #pragma unroll
  for (int j=0;j<16;j++) g[j]=0.f;
  float ps = 0.f;
  for (int o=0;o<64;o++){
    float x = h[o];
    #pragma unroll
    for (int j=0;j<16;j++) g[j] = fmaf(x, hg[o*16+j], g[j]);
    ps = fmaf(x, hs2[o], ps);
  }
  float pvx=0.f, pvy=0.f, pvz=0.f;
  #pragma unroll
  for (int j=0;j<16;j++){
    float gv = fsig(g[j]) * hv2[j];
    pvx = fmaf(v[(size_t)n*48+j*3+0], gv, pvx);
    pvy = fmaf(v[(size_t)n*48+j*3+1], gv, pvy);
    pvz = fmaf(v[(size_t)n*48+j*3+2], gv, pvz);
  }
  *(float4*)(out + (size_t)n*4) = make_float4(ps, pvx, pvy, pvz);
}

extern "C" void kernel_launch(void* const* d_in, const int* in_sizes, int n_in,
                              void* d_out, int out_size, void* d_ws, size_t ws_size,
                              hipStream_t stream)
{
  const float* pos       = (const float*)d_in[0];
  const int*   ei        = (const int*)  d_in[1];
  const int*   bond_mask = (const int*)  d_in[2];
  const int*   atom_type = (const int*)  d_in[3];
  const float* atom_emb  = (const float*)d_in[4];
  const float* bond_emb  = (const float*)d_in[5];
  const float* w_init    = (const float*)d_in[6];
  const float* mlp_w1    = (const float*)d_in[7];
  const float* mlp_b1    = (const float*)d_in[8];
  const float* mlp_w2    = (const float*)d_in[9];
  const float* lin_s     = (const float*)d_in[10];
  const float* lin_v     = (const float*)d_in[11];
  const float* gate_w    = (const float*)d_in[12];
  const float* hs1       = (const float*)d_in[13];
  const float* hg        = (const float*)d_in[14];
  const float* hs2       = (const float*)d_in[15];
  const float* hv2       = (const float*)d_in[16];
  float* out = (float*)d_out;

  char* ws = (char*)d_ws;
  size_t off_b = 0;
  auto alloc = [&](size_t nbytes){ void* p = (void*)(ws + off_b); off_b += ((nbytes + 255)/256)*256; return p; };
  uint4*    rec     = (uint4*)   alloc((size_t)N_EDGES*48);
  uint4*    msg4    = (uint4*)   alloc((size_t)N_EDGES*256);
  float*    sbuf    = (float*)   alloc((size_t)N_NODES*64*4);
  float*    vbuf    = (float*)   alloc((size_t)N_NODES*48*4);
  unsigned short* w2hi = (unsigned short*)alloc((size_t)3*176*64*2);
  int*      deg_src = (int*)     alloc((size_t)N_NODES*4);   // contiguous with deg_dst -> one memset
  int*      deg_dst = (int*)     alloc((size_t)N_NODES*4);
  int*      off_src = (int*)     alloc((size_t)(N_NODES+1)*4);
  int*      off_dst = (int*)     alloc((size_t)(N_NODES+1)*4);
  int*      cur_src = (int*)     alloc((size_t)N_NODES*4);
  int*      cur_dst = (int*)     alloc((size_t)N_NODES*4);
  int*      csr_src = (int*)     alloc((size_t)N_EDGES*4);
  int*      pos_src = (int*)     alloc((size_t)N_EDGES*4);
  int*      gidx    = (int*)     alloc((size_t)N_EDGES*4);

  dim3 blk(256);
  int gE = (N_EDGES + 255)/256;
  int gN = (N_NODES + 255)/256;
  int gG = (N_NODES + 15)/16;

  hipMemsetAsync(vbuf, 0, (size_t)N_NODES*48*sizeof(float), stream);
  hipMemsetAsync(deg_src, 0, (size_t)2*N_NODES*sizeof(int) + 512, stream);

  count2<<<gE, blk, 0, stream>>>(ei, deg_src, deg_dst);
  scan_deg2<<<2, 1024, 0, stream>>>(deg_src, off_src, cur_src, deg_dst, off_dst, cur_dst);
  scatter_src<<<gE, blk, 0, stream>>>(ei, cur_src, csr_src, pos_src);
  scatter_dst<<<gE, blk, 0, stream>>>(ei, pos_src, cur_dst, gidx);

  prep_edges2<<<gE, blk, 0, stream>>>(pos, ei, bond_mask, bond_emb, csr_src, rec);
  prep_weights<<<(3*176*64 + 255)/256, blk, 0, stream>>>(mlp_w2, w2hi);
  init_nodes<<<gN, blk, 0, stream>>>(atom_type, atom_emb, w_init, sbuf);

  for (int l=0;l<3;l++){
    edge_fused2<<<NBLK, blk, 0, stream>>>(rec, sbuf, vbuf,
        mlp_w1 + (size_t)l*16*64, mlp_b1 + (size_t)l*64,
        w2hi + (size_t)l*176*64,
        lin_v + (size_t)l*96*16,
        msg4);
    gather_update<<<gG, blk, 0, stream>>>(msg4, off_dst, gidx,
        lin_s + (size_t)l*80*64, gate_w + (size_t)l*64*16, sbuf, vbuf);
  }
  head_kernel<<<gN, blk, 0, stream>>>(sbuf, vbuf, hs1, hg, hs2, hv2, out);
}